// Round 1
// baseline (6077.010 us; speedup 1.0000x reference)
//
#include <hip/hip_runtime.h>

// GRU-D fused recurrent kernel, fp32 baseline.
// Each block owns BB=4 batch rows for the entire T=256 recurrence (no
// inter-block dependency). Weights stream from L2 each step; state (h,
// x_prev) lives in LDS.

constexpr int Bn  = 512;
constexpr int Tn  = 256;
constexpr int Dn  = 64;
constexpr int Hn  = 256;
constexpr int BB  = 4;     // batch rows per block
constexpr int NTH = 256;   // threads per block (4 waves)

__device__ __forceinline__ float sigmoidf_(float x) {
    return 1.0f / (1.0f + expf(-x));
}

__global__ __launch_bounds__(NTH) void grud_fused(
    const float* __restrict__ X, const float* __restrict__ M, const float* __restrict__ Dl,
    const float* __restrict__ x_mean,
    const float* __restrict__ W_gx, const float* __restrict__ b_gx,
    const float* __restrict__ W_gh, const float* __restrict__ b_gh,
    const float* __restrict__ W_x, const float* __restrict__ W_h, const float* __restrict__ W_m,
    const float* __restrict__ b_g,
    const float* __restrict__ W_cls, const float* __restrict__ b_cls,
    float* __restrict__ out)
{
    __shared__ float sh_h [BB][Hn];
    __shared__ float sh_hd[BB][Hn];
    __shared__ float sh_rhd[BB][Hn];
    __shared__ float sh_xp[BB][Dn];
    __shared__ float sh_xh[BB][Dn];
    __shared__ float sh_m [BB][Dn];
    __shared__ float sh_x [BB][Dn];
    __shared__ float sh_dl[BB][Dn];
    __shared__ float sh_xmean[Dn];
    __shared__ float sh_bgx[Dn];
    __shared__ float sh_bgh[Hn];
    __shared__ float sh_bg[3][Hn];

    const int tid = threadIdx.x;
    const int b0  = blockIdx.x * BB;

    // ---- init state + cache small vectors ----
    for (int i = tid; i < BB * Hn; i += NTH) (&sh_h[0][0])[i]  = 0.0f;
    for (int i = tid; i < BB * Dn; i += NTH) (&sh_xp[0][0])[i] = 0.0f;
    if (tid < Dn) { sh_xmean[tid] = x_mean[tid]; sh_bgx[tid] = b_gx[tid]; }
    sh_bgh[tid]   = b_gh[tid];
    sh_bg[0][tid] = b_g[0 * Hn + tid];
    sh_bg[1][tid] = b_g[1 * Hn + tid];
    sh_bg[2][tid] = b_g[2 * Hn + tid];
    __syncthreads();

    float zg[BB];

    for (int t = 0; t < Tn; ++t) {
        // ---- phase 1: load x, m, delta for BB rows ----
        {
            const int row = tid >> 6, d = tid & 63;
            const size_t off = ((size_t)(b0 + row) * Tn + (size_t)t) * Dn + d;
            sh_x [row][d] = X[off];
            sh_m [row][d] = M[off];
            sh_dl[row][d] = Dl[off];
        }
        __syncthreads();

        // ---- phase 2: gamma_x, x_hat, x_prev update (one (row,d) per thread) ----
        {
            const int row = tid >> 6, d = tid & 63;
            float acc = sh_bgx[d];
            #pragma unroll 8
            for (int k = 0; k < Dn; ++k)
                acc = fmaf(sh_dl[row][k], W_gx[k * Dn + d], acc);
            const float gx  = expf(-fmaxf(acc, 0.0f));
            const float mv  = sh_m[row][d], xv = sh_x[row][d], xpv = sh_xp[row][d];
            sh_xh[row][d] = mv * xv + (1.0f - mv) * (gx * xpv + (1.0f - gx) * sh_xmean[d]);
            sh_xp[row][d] = mv * xv + (1.0f - mv) * xpv;   // carry last observation
        }

        // ---- phase 3: gamma_h, hd (thread = col j, all BB rows) ----
        {
            const int j = tid;
            float a0 = sh_bgh[j], a1 = a0, a2 = a0, a3 = a0;
            #pragma unroll 8
            for (int k = 0; k < Dn; ++k) {
                const float w = W_gh[k * Hn + j];
                a0 = fmaf(sh_dl[0][k], w, a0);
                a1 = fmaf(sh_dl[1][k], w, a1);
                a2 = fmaf(sh_dl[2][k], w, a2);
                a3 = fmaf(sh_dl[3][k], w, a3);
            }
            sh_hd[0][j] = expf(-fmaxf(a0, 0.0f)) * sh_h[0][j];
            sh_hd[1][j] = expf(-fmaxf(a1, 0.0f)) * sh_h[1][j];
            sh_hd[2][j] = expf(-fmaxf(a2, 0.0f)) * sh_h[2][j];
            sh_hd[3][j] = expf(-fmaxf(a3, 0.0f)) * sh_h[3][j];
        }
        __syncthreads();

        // ---- phase 4: z and r gates (thread = col j, all BB rows) ----
        {
            const int j = tid;
            float az[BB], ar[BB];
            #pragma unroll
            for (int rI = 0; rI < BB; ++rI) { az[rI] = sh_bg[0][j]; ar[rI] = sh_bg[1][j]; }

            // input-dim part (x_hat @ W_x, m @ W_m)
            #pragma unroll 2
            for (int k4 = 0; k4 < Dn / 4; ++k4) {
                float4 xhv[BB], mv[BB];
                #pragma unroll
                for (int rI = 0; rI < BB; ++rI) {
                    xhv[rI] = *reinterpret_cast<const float4*>(&sh_xh[rI][k4 * 4]);
                    mv[rI]  = *reinterpret_cast<const float4*>(&sh_m [rI][k4 * 4]);
                }
                #pragma unroll
                for (int kk = 0; kk < 4; ++kk) {
                    const int k = k4 * 4 + kk;
                    const float wzx = W_x[0 * Dn * Hn + k * Hn + j];
                    const float wrx = W_x[1 * Dn * Hn + k * Hn + j];
                    const float wzm = W_m[0 * Dn * Hn + k * Hn + j];
                    const float wrm = W_m[1 * Dn * Hn + k * Hn + j];
                    #pragma unroll
                    for (int rI = 0; rI < BB; ++rI) {
                        const float xk = ((const float*)&xhv[rI])[kk];
                        const float mk = ((const float*)&mv[rI])[kk];
                        az[rI] = fmaf(xk, wzx, fmaf(mk, wzm, az[rI]));
                        ar[rI] = fmaf(xk, wrx, fmaf(mk, wrm, ar[rI]));
                    }
                }
            }
            // hidden part (hd @ W_h[0], hd @ W_h[1])
            #pragma unroll 2
            for (int k4 = 0; k4 < Hn / 4; ++k4) {
                float4 hdv[BB];
                #pragma unroll
                for (int rI = 0; rI < BB; ++rI)
                    hdv[rI] = *reinterpret_cast<const float4*>(&sh_hd[rI][k4 * 4]);
                #pragma unroll
                for (int kk = 0; kk < 4; ++kk) {
                    const int k = k4 * 4 + kk;
                    const float wz = W_h[0 * Hn * Hn + k * Hn + j];
                    const float wr = W_h[1 * Hn * Hn + k * Hn + j];
                    #pragma unroll
                    for (int rI = 0; rI < BB; ++rI) {
                        const float hk = ((const float*)&hdv[rI])[kk];
                        az[rI] = fmaf(hk, wz, az[rI]);
                        ar[rI] = fmaf(hk, wr, ar[rI]);
                    }
                }
            }
            #pragma unroll
            for (int rI = 0; rI < BB; ++rI) {
                zg[rI] = sigmoidf_(az[rI]);
                const float rr = sigmoidf_(ar[rI]);
                sh_rhd[rI][j] = rr * sh_hd[rI][j];
            }
        }
        __syncthreads();

        // ---- phase 5: h_tilde and h update ----
        {
            const int j = tid;
            float ah[BB];
            #pragma unroll
            for (int rI = 0; rI < BB; ++rI) ah[rI] = sh_bg[2][j];

            #pragma unroll 2
            for (int k4 = 0; k4 < Dn / 4; ++k4) {
                float4 xhv[BB], mv[BB];
                #pragma unroll
                for (int rI = 0; rI < BB; ++rI) {
                    xhv[rI] = *reinterpret_cast<const float4*>(&sh_xh[rI][k4 * 4]);
                    mv[rI]  = *reinterpret_cast<const float4*>(&sh_m [rI][k4 * 4]);
                }
                #pragma unroll
                for (int kk = 0; kk < 4; ++kk) {
                    const int k = k4 * 4 + kk;
                    const float wx = W_x[2 * Dn * Hn + k * Hn + j];
                    const float wm = W_m[2 * Dn * Hn + k * Hn + j];
                    #pragma unroll
                    for (int rI = 0; rI < BB; ++rI) {
                        const float xk = ((const float*)&xhv[rI])[kk];
                        const float mk = ((const float*)&mv[rI])[kk];
                        ah[rI] = fmaf(xk, wx, fmaf(mk, wm, ah[rI]));
                    }
                }
            }
            #pragma unroll 2
            for (int k4 = 0; k4 < Hn / 4; ++k4) {
                float4 rv[BB];
                #pragma unroll
                for (int rI = 0; rI < BB; ++rI)
                    rv[rI] = *reinterpret_cast<const float4*>(&sh_rhd[rI][k4 * 4]);
                #pragma unroll
                for (int kk = 0; kk < 4; ++kk) {
                    const int k = k4 * 4 + kk;
                    const float wh = W_h[2 * Hn * Hn + k * Hn + j];
                    #pragma unroll
                    for (int rI = 0; rI < BB; ++rI) {
                        const float rk = ((const float*)&rv[rI])[kk];
                        ah[rI] = fmaf(rk, wh, ah[rI]);
                    }
                }
            }
            #pragma unroll
            for (int rI = 0; rI < BB; ++rI) {
                const float ht  = tanhf(ah[rI]);
                const float hdv = sh_hd[rI][j];
                sh_h[rI][j] = (1.0f - zg[rI]) * hdv + zg[rI] * ht;
            }
        }
        __syncthreads();
    }

    // ---- classifier: out[b] = h[b,:] @ W_cls + b_cls ----
    {
        const int row = tid >> 6, lane = tid & 63;
        float p = 0.0f;
        #pragma unroll
        for (int jj = 0; jj < Hn / 64; ++jj)
            p = fmaf(sh_h[row][lane + jj * 64], W_cls[lane + jj * 64], p);
        #pragma unroll
        for (int o = 32; o > 0; o >>= 1) p += __shfl_down(p, o, 64);
        if (lane == 0) out[b0 + row] = p + b_cls[0];
    }
}

extern "C" void kernel_launch(void* const* d_in, const int* in_sizes, int n_in,
                              void* d_out, int out_size, void* d_ws, size_t ws_size,
                              hipStream_t stream) {
    const float* X      = (const float*)d_in[0];
    const float* M      = (const float*)d_in[1];
    const float* Dl     = (const float*)d_in[2];
    const float* x_mean = (const float*)d_in[3];
    const float* W_gx   = (const float*)d_in[4];
    const float* b_gx   = (const float*)d_in[5];
    const float* W_gh   = (const float*)d_in[6];
    const float* b_gh   = (const float*)d_in[7];
    const float* W_x    = (const float*)d_in[8];
    const float* W_h    = (const float*)d_in[9];
    const float* W_m    = (const float*)d_in[10];
    const float* b_g    = (const float*)d_in[11];
    const float* W_cls  = (const float*)d_in[12];
    const float* b_cls  = (const float*)d_in[13];
    float* out = (float*)d_out;

    hipLaunchKernelGGL(grud_fused, dim3(Bn / BB), dim3(NTH), 0, stream,
                       X, M, Dl, x_mean, W_gx, b_gx, W_gh, b_gh,
                       W_x, W_h, W_m, b_g, W_cls, b_cls, out);
}

// Round 2
// 2903.311 us; speedup vs baseline: 2.0931x; 2.0931x over previous
//
#include <hip/hip_runtime.h>

// GRU-D fully-fused MFMA kernel.
// 32 blocks x 512 threads; each block owns 16 batch rows (= MFMA M-tile) for
// the whole T=256 recurrence. All GEMVs run on v_mfma_f32_16x16x32_bf16 with
// fp32 accumulation. Weights are packed once per launch into B-fragment
// layout (bf16) in d_ws; A-fragments are rebuilt in LDS each step.
//
// Verified layouts (learn_hip m89/m91/m92):
//   A (M=16 x K=32): lane l holds A[row=l&15][k=(l>>4)*8+i], i=0..7 (bf16x8)
//   B (K=32 x N=16): lane l holds B[k=(l>>4)*8+i][col=l&15]
//   C/D (16x16 f32x4): col=lane&15, row=(lane>>4)*4+reg

constexpr int Bn = 512, Tn = 256, Dn = 64, Hn = 256;
constexpr int BB = 16, NTH = 512, NBLK = Bn / BB;   // 32 blocks

typedef __attribute__((ext_vector_type(8))) short bf8_t;   // 8 x bf16 bits
typedef __attribute__((ext_vector_type(4))) float f4_t;    // MFMA accumulator

// pack region offsets in shorts (bf16 elements), regions back-to-back
constexpr size_t OFF_WH  = 0;        // 3 * 16nt * 8kt * 64 * 8 = 196608
constexpr size_t OFF_WX  = 196608;   // 3 * 16nt * 2kt * 64 * 8 = 49152
constexpr size_t OFF_WM  = 245760;   // 49152
constexpr size_t OFF_WGH = 294912;   // 16nt * 2kt * 64 * 8 = 16384
constexpr size_t OFF_WGX = 311296;   // 4nt  * 2kt * 64 * 8 = 4096
constexpr int    PACK_SLOTS = 39424; // total 16B lane-slots (x8 shorts)

__device__ __forceinline__ unsigned short f2bf(float x) {
    union { float f; unsigned int u; } v; v.f = x;
    unsigned int r = (v.u + 0x7fffu + ((v.u >> 16) & 1u)) >> 16;   // RNE
    return (unsigned short)r;
}

__global__ __launch_bounds__(256) void pack_weights(
    const float* __restrict__ W_gx, const float* __restrict__ W_gh,
    const float* __restrict__ W_x,  const float* __restrict__ W_h,
    const float* __restrict__ W_m,  short* __restrict__ out)
{
    const int slot = blockIdx.x * 256 + threadIdx.x;
    if (slot >= PACK_SLOTS) return;

    const float* w; int ldn, l, kt, j, kbase;
    if (slot < 24576) {                       // W_h: per gate 16nt*8kt*64 = 8192 slots
        int g = slot >> 13, rem = slot & 8191;
        int ntG = rem >> 9, r2 = rem & 511;
        kt = r2 >> 6; l = r2 & 63;
        j = ntG * 16 + (l & 15);
        w = W_h + (size_t)g * Hn * Hn; ldn = Hn;
    } else if (slot < 30720) {                // W_x: per gate 16nt*2kt*64 = 2048 slots
        int s = slot - 24576;
        int g = s >> 11, rem = s & 2047;
        int ntG = rem >> 7, r2 = rem & 127;
        kt = r2 >> 6; l = r2 & 63;
        j = ntG * 16 + (l & 15);
        w = W_x + (size_t)g * Dn * Hn; ldn = Hn;
    } else if (slot < 36864) {                // W_m
        int s = slot - 30720;
        int g = s >> 11, rem = s & 2047;
        int ntG = rem >> 7, r2 = rem & 127;
        kt = r2 >> 6; l = r2 & 63;
        j = ntG * 16 + (l & 15);
        w = W_m + (size_t)g * Dn * Hn; ldn = Hn;
    } else if (slot < 38912) {                // W_gh: 16nt*2kt*64 = 2048 slots
        int s = slot - 36864;
        int ntG = s >> 7, r2 = s & 127;
        kt = r2 >> 6; l = r2 & 63;
        j = ntG * 16 + (l & 15);
        w = W_gh; ldn = Hn;
    } else {                                  // W_gx: 4nt*2kt*64 = 512 slots
        int s = slot - 38912;
        int ntG = s >> 7, r2 = s & 127;
        kt = r2 >> 6; l = r2 & 63;
        j = ntG * 16 + (l & 15);
        w = W_gx; ldn = Dn;
    }
    kbase = kt * 32 + ((l >> 4) << 3);
    bf8_t v;
    #pragma unroll
    for (int i = 0; i < 8; ++i)
        v[i] = (short)f2bf(w[(size_t)(kbase + i) * ldn + j]);
    *(bf8_t*)&out[(size_t)slot * 8] = v;
}

__device__ __forceinline__ f4_t MF(bf8_t a, const short* bp, f4_t c) {
    bf8_t b = *(const bf8_t*)bp;
    return __builtin_amdgcn_mfma_f32_16x16x32_bf16(a, b, c, 0, 0, 0);
}
// B-frag address: p + ((ntG*KT + kt)*64 + lane)*8
__device__ __forceinline__ const short* BA(const short* p, int ntG, int KT, int kt, int lane) {
    return p + (((size_t)ntG * KT + kt) * 64 + lane) * 8;
}

__global__ __launch_bounds__(NTH, 2) void grud_main(
    const float* __restrict__ X, const float* __restrict__ M, const float* __restrict__ Dl,
    const float* __restrict__ x_mean, const float* __restrict__ b_gx,
    const float* __restrict__ b_gh, const float* __restrict__ b_g,
    const float* __restrict__ W_cls, const float* __restrict__ b_cls,
    const short* __restrict__ pk, float* __restrict__ out)
{
    __shared__ float sh_h [BB][Hn];     // 16 KB  hidden state (fp32)
    __shared__ float sh_xp[BB][Dn];     // x_prev
    __shared__ float sh_x [BB][Dn];
    __shared__ float sh_m [BB][Dn];
    __shared__ short sA_d  [2 * 64 * 8];   // A-frags, K=64 (2 ktiles)
    __shared__ short sA_m  [2 * 64 * 8];
    __shared__ short sA_xh [2 * 64 * 8];
    __shared__ short sA_hd [8 * 64 * 8];   // A-frags, K=256 (8 ktiles)
    __shared__ short sA_rhd[8 * 64 * 8];
    __shared__ float sh_bgx[Dn], sh_xmean[Dn], sh_bgh[Hn], sh_bg[3][Hn];

    const int tid  = threadIdx.x;
    const int w    = tid >> 6, lane = tid & 63;
    const int b0   = blockIdx.x * BB;
    const int rowb = (lane >> 4) * 4;   // C/D row base
    const int c15  = lane & 15;         // C/D col within ntile

    for (int i = tid; i < BB * Hn; i += NTH) (&sh_h[0][0])[i]  = 0.f;
    for (int i = tid; i < BB * Dn; i += NTH) (&sh_xp[0][0])[i] = 0.f;
    if (tid < Dn) { sh_bgx[tid] = b_gx[tid]; sh_xmean[tid] = x_mean[tid]; }
    if (tid < Hn) sh_bgh[tid] = b_gh[tid];
    for (int i = tid; i < 3 * Hn; i += NTH) (&sh_bg[0][0])[i] = b_g[i];
    __syncthreads();

    const short* whp  = pk + OFF_WH;
    const short* wxp  = pk + OFF_WX;
    const short* wmp  = pk + OFF_WM;
    const short* wghp = pk + OFF_WGH;
    const short* wgxp = pk + OFF_WGX;

    for (int t = 0; t < Tn; ++t) {
        // ---------- stage: x/m tiles (fp32) + d/m A-frags (bf16) ----------
        if (tid < 128) {                       // d A-frags
            const int kt2 = tid >> 6, lf = tid & 63;
            const int r = lf & 15, db = kt2 * 32 + ((lf >> 4) << 3);
            const float* p = Dl + ((size_t)(b0 + r) * Tn + t) * Dn + db;
            float4 a = *(const float4*)p, b = *(const float4*)(p + 4);
            bf8_t v;
            v[0]=f2bf(a.x); v[1]=f2bf(a.y); v[2]=f2bf(a.z); v[3]=f2bf(a.w);
            v[4]=f2bf(b.x); v[5]=f2bf(b.y); v[6]=f2bf(b.z); v[7]=f2bf(b.w);
            *(bf8_t*)&sA_d[tid * 8] = v;
        } else if (tid < 256) {                // m A-frags
            const int s = tid - 128;
            const int kt2 = s >> 6, lf = s & 63;
            const int r = lf & 15, db = kt2 * 32 + ((lf >> 4) << 3);
            const float* p = M + ((size_t)(b0 + r) * Tn + t) * Dn + db;
            float4 a = *(const float4*)p, b = *(const float4*)(p + 4);
            bf8_t v;
            v[0]=f2bf(a.x); v[1]=f2bf(a.y); v[2]=f2bf(a.z); v[3]=f2bf(a.w);
            v[4]=f2bf(b.x); v[5]=f2bf(b.y); v[6]=f2bf(b.z); v[7]=f2bf(b.w);
            *(bf8_t*)&sA_m[s * 8] = v;
        } else {                               // x, m fp32 tiles
            const int s = tid - 256, r = s >> 4, seg = (s & 15) * 4;
            const size_t off = ((size_t)(b0 + r) * Tn + t) * Dn + seg;
            *(float4*)&sh_x[r][seg] = *(const float4*)(X + off);
            *(float4*)&sh_m[r][seg] = *(const float4*)(M + off);
        }
        __syncthreads();

        // ---------- phase 1: gamma_h GEMM (all waves) + gamma_x/x_hat (waves 0-3) ----------
        bf8_t df0 = *(const bf8_t*)&sA_d[(0 * 64 + lane) * 8];
        bf8_t df1 = *(const bf8_t*)&sA_d[(1 * 64 + lane) * 8];
        f4_t accG0 = {0.f,0.f,0.f,0.f}, accG1 = {0.f,0.f,0.f,0.f};
        accG0 = MF(df0, BA(wghp, 2*w+0, 2, 0, lane), accG0);
        accG0 = MF(df1, BA(wghp, 2*w+0, 2, 1, lane), accG0);
        accG1 = MF(df0, BA(wghp, 2*w+1, 2, 0, lane), accG1);
        accG1 = MF(df1, BA(wghp, 2*w+1, 2, 1, lane), accG1);
        if (w < 4) {
            f4_t aGx = {0.f,0.f,0.f,0.f};
            aGx = MF(df0, BA(wgxp, w, 2, 0, lane), aGx);
            aGx = MF(df1, BA(wgxp, w, 2, 1, lane), aGx);
            const int col = w * 16 + c15;
            #pragma unroll
            for (int q = 0; q < 4; ++q) {
                const int r = rowb + q;
                float gx  = __expf(-fmaxf(aGx[q] + sh_bgx[col], 0.f));
                float mv  = sh_m[r][col], xv = sh_x[r][col], xpv = sh_xp[r][col];
                float xh  = mv * xv + (1.f - mv) * (gx * xpv + (1.f - gx) * sh_xmean[col]);
                sh_xp[r][col] = mv * xv + (1.f - mv) * xpv;
                sA_xh[((col >> 5) * 64 + (((col & 31) >> 3) << 4) + r) * 8 + (col & 7)]
                    = (short)f2bf(xh);
            }
        }
        __syncthreads();

        // ---------- phase 2: P-gate GEMMs (x_hat@W_x + m@W_m) + hd build ----------
        bf8_t xf0 = *(const bf8_t*)&sA_xh[(0 * 64 + lane) * 8];
        bf8_t xf1 = *(const bf8_t*)&sA_xh[(1 * 64 + lane) * 8];
        bf8_t mf0 = *(const bf8_t*)&sA_m [(0 * 64 + lane) * 8];
        bf8_t mf1 = *(const bf8_t*)&sA_m [(1 * 64 + lane) * 8];
        f4_t accP[3][2];
        #pragma unroll
        for (int g = 0; g < 3; ++g) {
            const short* bx = wxp + (size_t)g * 16384;
            const short* bm = wmp + (size_t)g * 16384;
            #pragma unroll
            for (int nt = 0; nt < 2; ++nt) {
                const int ntG = 2 * w + nt;
                f4_t a = {0.f,0.f,0.f,0.f};
                a = MF(xf0, BA(bx, ntG, 2, 0, lane), a);
                a = MF(xf1, BA(bx, ntG, 2, 1, lane), a);
                a = MF(mf0, BA(bm, ntG, 2, 0, lane), a);
                a = MF(mf1, BA(bm, ntG, 2, 1, lane), a);
                accP[g][nt] = a;
            }
        }
        float hd[2][4];
        #pragma unroll
        for (int nt = 0; nt < 2; ++nt) {
            const f4_t aG = nt ? accG1 : accG0;
            const int col = w * 32 + nt * 16 + c15;
            #pragma unroll
            for (int q = 0; q < 4; ++q) {
                const int r = rowb + q;
                float gh  = __expf(-fmaxf(aG[q] + sh_bgh[col], 0.f));
                float hdv = gh * sh_h[r][col];
                hd[nt][q] = hdv;
                sA_hd[((size_t)w * 64 + (((col & 31) >> 3) << 4) + r) * 8 + (col & 7)]
                    = (short)f2bf(hdv);
            }
        }
        __syncthreads();

        // ---------- phase 3: z and r gates (hd @ W_h[0,1]) ----------
        f4_t accZ[2] = {accP[0][0], accP[0][1]};
        f4_t accR[2] = {accP[1][0], accP[1][1]};
        #pragma unroll
        for (int kt = 0; kt < 8; ++kt) {
            bf8_t hf = *(const bf8_t*)&sA_hd[(kt * 64 + lane) * 8];
            #pragma unroll
            for (int nt = 0; nt < 2; ++nt) {
                const int ntG = 2 * w + nt;
                accZ[nt] = MF(hf, BA(whp + 0 * 65536, ntG, 8, kt, lane), accZ[nt]);
                accR[nt] = MF(hf, BA(whp + 1 * 65536, ntG, 8, kt, lane), accR[nt]);
            }
        }
        float zz[2][4];
        #pragma unroll
        for (int nt = 0; nt < 2; ++nt) {
            const int col = w * 32 + nt * 16 + c15;
            #pragma unroll
            for (int q = 0; q < 4; ++q) {
                const int r = rowb + q;
                float z  = 1.f / (1.f + __expf(-(accZ[nt][q] + sh_bg[0][col])));
                float rr = 1.f / (1.f + __expf(-(accR[nt][q] + sh_bg[1][col])));
                zz[nt][q] = z;
                sA_rhd[((size_t)w * 64 + (((col & 31) >> 3) << 4) + r) * 8 + (col & 7)]
                    = (short)f2bf(rr * hd[nt][q]);
            }
        }
        __syncthreads();

        // ---------- phase 4: h_tilde ((r*hd) @ W_h[2]) + h update ----------
        f4_t accH[2] = {accP[2][0], accP[2][1]};
        #pragma unroll
        for (int kt = 0; kt < 8; ++kt) {
            bf8_t hf = *(const bf8_t*)&sA_rhd[(kt * 64 + lane) * 8];
            #pragma unroll
            for (int nt = 0; nt < 2; ++nt)
                accH[nt] = MF(hf, BA(whp + 2 * 65536, 2 * w + nt, 8, kt, lane), accH[nt]);
        }
        #pragma unroll
        for (int nt = 0; nt < 2; ++nt) {
            const int col = w * 32 + nt * 16 + c15;
            #pragma unroll
            for (int q = 0; q < 4; ++q) {
                const int r = rowb + q;
                float pre = accH[nt][q] + sh_bg[2][col];
                float a = fabsf(pre), e = __expf(-2.f * a);
                float th = copysignf((1.f - e) / (1.f + e), pre);
                sh_h[r][col] = (1.f - zz[nt][q]) * hd[nt][q] + zz[nt][q] * th;
            }
        }
        __syncthreads();
    }

    // ---------- classifier ----------
    if (tid < BB) {
        float s = 0.f;
        for (int k = 0; k < Hn; ++k) s = fmaf(sh_h[tid][k], W_cls[k], s);
        out[b0 + tid] = s + b_cls[0];
    }
}

extern "C" void kernel_launch(void* const* d_in, const int* in_sizes, int n_in,
                              void* d_out, int out_size, void* d_ws, size_t ws_size,
                              hipStream_t stream) {
    const float* X      = (const float*)d_in[0];
    const float* M      = (const float*)d_in[1];
    const float* Dl     = (const float*)d_in[2];
    const float* x_mean = (const float*)d_in[3];
    const float* W_gx   = (const float*)d_in[4];
    const float* b_gx   = (const float*)d_in[5];
    const float* W_gh   = (const float*)d_in[6];
    const float* b_gh   = (const float*)d_in[7];
    const float* W_x    = (const float*)d_in[8];
    const float* W_h    = (const float*)d_in[9];
    const float* W_m    = (const float*)d_in[10];
    const float* b_g    = (const float*)d_in[11];
    const float* W_cls  = (const float*)d_in[12];
    const float* b_cls  = (const float*)d_in[13];
    float* out = (float*)d_out;
    short* pk  = (short*)d_ws;    // 630,784 bytes of packed bf16 weights

    hipLaunchKernelGGL(pack_weights, dim3(PACK_SLOTS / 256), dim3(256), 0, stream,
                       W_gx, W_gh, W_x, W_h, W_m, pk);
    hipLaunchKernelGGL(grud_main, dim3(NBLK), dim3(NTH), 0, stream,
                       X, M, Dl, x_mean, b_gx, b_gh, b_g, W_cls, b_cls, pk, out);
}

// Round 3
// 2433.685 us; speedup vs baseline: 2.4970x; 1.1930x over previous
//
#include <hip/hip_runtime.h>

// GRU-D, round 3.
// Plan: pack_weights -> prepass (gamma_x/gamma_h precompute, parallel) ->
// grud_rec (fused recurrence, 32 blocks x 512 thr, all weights streamed
// from L2 into registers issued a phase ahead; W_x LDS-resident).
// Fallback to round-2 kernel if ws_size is too small for gamma buffers.

constexpr int Bn = 512, Tn = 256, Dn = 64, Hn = 256;
constexpr int BB = 16, NBLK = Bn / BB;   // 32 blocks

typedef __attribute__((ext_vector_type(8))) short bf8_t;   // 8 x bf16 bits
typedef __attribute__((ext_vector_type(4))) float f4_t;    // MFMA accumulator

// packed-weight region offsets in shorts
constexpr size_t OFF_WH  = 0;        // 3 * 16nt * 8kt * 64 * 8
constexpr size_t OFF_WX  = 196608;   // 3 * 16nt * 2kt * 64 * 8
constexpr size_t OFF_WM  = 245760;
constexpr size_t OFF_WGH = 294912;   // 16nt * 2kt * 64 * 8
constexpr size_t OFF_WGX = 311296;   // 4nt * 2kt * 64 * 8
constexpr int    PACK_SLOTS = 39424;

// workspace layout (bytes)
constexpr size_t GX_OFF  = (size_t)1 << 20;                      // gamma_x f32 [B][T][D]
constexpr size_t GH_OFF  = GX_OFF + (size_t)Bn * Tn * Dn * 4;    // gamma_h bf16 [B][T][H]
constexpr size_t WS_NEED = GH_OFF + (size_t)Bn * Tn * Hn * 2;    // = 101,711,872

__device__ __forceinline__ unsigned short f2bf(float x) {
    union { float f; unsigned int u; } v; v.f = x;
    unsigned int r = (v.u + 0x7fffu + ((v.u >> 16) & 1u)) >> 16;   // RNE
    return (unsigned short)r;
}
__device__ __forceinline__ float bf2f(unsigned short u) {
    union { unsigned int i; float f; } v; v.i = ((unsigned int)u) << 16; return v.f;
}
__device__ __forceinline__ bf8_t LD8(const short* p) { return *(const bf8_t*)p; }

__device__ __forceinline__ f4_t MF(bf8_t a, bf8_t b, f4_t c) {
    return __builtin_amdgcn_mfma_f32_16x16x32_bf16(a, b, c, 0, 0, 0);
}
__device__ __forceinline__ f4_t MFp(bf8_t a, const short* bp, f4_t c) {
    return MF(a, LD8(bp), c);
}
// B-frag address: p + ((ntG*KT + kt)*64 + lane)*8
__device__ __forceinline__ const short* BA(const short* p, int ntG, int KT, int kt, int lane) {
    return p + (((size_t)ntG * KT + kt) * 64 + lane) * 8;
}

// ---------------------------------------------------------------------------
// pack_weights: fp32 weights -> bf16 B-fragment layout (unchanged from R2)
// ---------------------------------------------------------------------------
__global__ __launch_bounds__(256) void pack_weights(
    const float* __restrict__ W_gx, const float* __restrict__ W_gh,
    const float* __restrict__ W_x,  const float* __restrict__ W_h,
    const float* __restrict__ W_m,  short* __restrict__ out)
{
    const int slot = blockIdx.x * 256 + threadIdx.x;
    if (slot >= PACK_SLOTS) return;

    const float* w; int ldn, l, kt, j, kbase;
    if (slot < 24576) {                       // W_h
        int g = slot >> 13, rem = slot & 8191;
        int ntG = rem >> 9, r2 = rem & 511;
        kt = r2 >> 6; l = r2 & 63;
        j = ntG * 16 + (l & 15);
        w = W_h + (size_t)g * Hn * Hn; ldn = Hn;
    } else if (slot < 30720) {                // W_x
        int s = slot - 24576;
        int g = s >> 11, rem = s & 2047;
        int ntG = rem >> 7, r2 = rem & 127;
        kt = r2 >> 6; l = r2 & 63;
        j = ntG * 16 + (l & 15);
        w = W_x + (size_t)g * Dn * Hn; ldn = Hn;
    } else if (slot < 36864) {                // W_m
        int s = slot - 30720;
        int g = s >> 11, rem = s & 2047;
        int ntG = rem >> 7, r2 = rem & 127;
        kt = r2 >> 6; l = r2 & 63;
        j = ntG * 16 + (l & 15);
        w = W_m + (size_t)g * Dn * Hn; ldn = Hn;
    } else if (slot < 38912) {                // W_gh
        int s = slot - 36864;
        int ntG = s >> 7, r2 = s & 127;
        kt = r2 >> 6; l = r2 & 63;
        j = ntG * 16 + (l & 15);
        w = W_gh; ldn = Hn;
    } else {                                  // W_gx
        int s = slot - 38912;
        int ntG = s >> 7, r2 = s & 127;
        kt = r2 >> 6; l = r2 & 63;
        j = ntG * 16 + (l & 15);
        w = W_gx; ldn = Dn;
    }
    kbase = kt * 32 + ((l >> 4) << 3);
    bf8_t v;
    #pragma unroll
    for (int i = 0; i < 8; ++i)
        v[i] = (short)f2bf(w[(size_t)(kbase + i) * ldn + j]);
    *(bf8_t*)&out[(size_t)slot * 8] = v;
}

// ---------------------------------------------------------------------------
// prepass: gamma_x (f32) and gamma_h (bf16) for all (b,t). grid = 32*256.
// ---------------------------------------------------------------------------
__global__ __launch_bounds__(256) void grud_prepass(
    const float* __restrict__ Dl, const float* __restrict__ b_gx,
    const float* __restrict__ b_gh, const short* __restrict__ pk,
    float* __restrict__ gx, unsigned short* __restrict__ gh)
{
    __shared__ short sDf[2 * 64 * 8];
    const int tid = threadIdx.x, w = tid >> 6, lane = tid & 63;
    const int bt = blockIdx.x >> 8, t = blockIdx.x & 255;
    const int b0 = bt * 16;
    const int c15 = lane & 15, rowb = (lane >> 4) * 4;

    if (w < 2) {   // build d A-frags
        const int row = lane & 15, cb = w * 32 + ((lane >> 4) << 3);
        const float* p = Dl + ((size_t)(b0 + row) * Tn + t) * Dn + cb;
        float4 a = *(const float4*)p, b = *(const float4*)(p + 4);
        bf8_t v;
        v[0]=(short)f2bf(a.x); v[1]=(short)f2bf(a.y); v[2]=(short)f2bf(a.z); v[3]=(short)f2bf(a.w);
        v[4]=(short)f2bf(b.x); v[5]=(short)f2bf(b.y); v[6]=(short)f2bf(b.z); v[7]=(short)f2bf(b.w);
        *(bf8_t*)&sDf[(w * 64 + lane) * 8] = v;
    }
    __syncthreads();
    bf8_t df0 = *(const bf8_t*)&sDf[lane * 8];
    bf8_t df1 = *(const bf8_t*)&sDf[(64 + lane) * 8];

    // gamma_h: ntiles 4w..4w+3
    #pragma unroll
    for (int i = 0; i < 4; ++i) {
        const int ntG = 4 * w + i;
        f4_t acc = {0.f, 0.f, 0.f, 0.f};
        acc = MFp(df0, BA(pk + OFF_WGH, ntG, 2, 0, lane), acc);
        acc = MFp(df1, BA(pk + OFF_WGH, ntG, 2, 1, lane), acc);
        const int col = ntG * 16 + c15;
        const float bb = b_gh[col];
        #pragma unroll
        for (int q = 0; q < 4; ++q) {
            const int r = rowb + q;
            gh[((size_t)(b0 + r) * Tn + t) * Hn + col] =
                f2bf(__expf(-fmaxf(acc[q] + bb, 0.f)));
        }
    }
    // gamma_x: ntile = w
    {
        f4_t acc = {0.f, 0.f, 0.f, 0.f};
        acc = MFp(df0, BA(pk + OFF_WGX, w, 2, 0, lane), acc);
        acc = MFp(df1, BA(pk + OFF_WGX, w, 2, 1, lane), acc);
        const int col = w * 16 + c15;
        const float bb = b_gx[col];
        #pragma unroll
        for (int q = 0; q < 4; ++q) {
            const int r = rowb + q;
            gx[((size_t)(b0 + r) * Tn + t) * Dn + col] =
                __expf(-fmaxf(acc[q] + bb, 0.f));
        }
    }
}

// ---------------------------------------------------------------------------
// grud_rec: fused recurrence. 32 blocks x 512 threads.
// ---------------------------------------------------------------------------
__global__ __launch_bounds__(512) void grud_rec(
    const float* __restrict__ X, const float* __restrict__ M,
    const float* __restrict__ x_mean, const float* __restrict__ b_g,
    const float* __restrict__ W_cls, const float* __restrict__ b_cls,
    const short* __restrict__ pk, const float* __restrict__ gx,
    const unsigned short* __restrict__ gh, float* __restrict__ out)
{
    __shared__ float sh_h[16][260];              // h state, padded (16640 B)
    __shared__ unsigned short gh_t[2][16 * 264]; // gamma_h tiles, padded (16896 B)
    __shared__ short sA_xh[2 * 64 * 8];
    __shared__ short sA_m [2 * 64 * 8];
    __shared__ short sA_hd[8 * 64 * 8];
    __shared__ short sA_rhd[8 * 64 * 8];
    __shared__ short sWx[3 * 16 * 2 * 64 * 8];   // W_x frags (98304 B)

    const int tid = threadIdx.x, w = tid >> 6, lane = tid & 63;
    const int c15 = lane & 15, rowb = (lane >> 4) * 4;
    const int b0 = blockIdx.x * BB;

    for (int i = tid; i < 16 * 260; i += 512) (&sh_h[0][0])[i] = 0.f;
    for (int c = tid; c < 6144; c += 512)
        *(uint4*)&sWx[c * 8] = *(const uint4*)&pk[OFF_WX + (size_t)c * 8];

    const float bz[2] = { b_g[0 * Hn + w * 32 + c15], b_g[0 * Hn + w * 32 + 16 + c15] };
    const float brr[2]= { b_g[1 * Hn + w * 32 + c15], b_g[1 * Hn + w * 32 + 16 + c15] };
    const float bh[2] = { b_g[2 * Hn + w * 32 + c15], b_g[2 * Hn + w * 32 + 16 + c15] };

    // builder mapping: subslot s -> (kt2, frag-lane, half): 4 cols each
    const int s    = w * 32 + (lane & 31);
    const int kt2  = s >> 7, fl = (s >> 1) & 63, half = s & 1;
    const int brow = fl & 15, bcol = kt2 * 32 + ((fl >> 4) << 3) + half * 4;
    const size_t brow_base = ((size_t)(b0 + brow) * Tn) * Dn + bcol;

    float xb[4] = {0.f, 0.f, 0.f, 0.f};
    float xp[4] = {0.f, 0.f, 0.f, 0.f};
    float4 mv, xv = {0,0,0,0}, gxv = {0,0,0,0};
    if (lane < 32) {
        xb[0]=x_mean[bcol]; xb[1]=x_mean[bcol+1]; xb[2]=x_mean[bcol+2]; xb[3]=x_mean[bcol+3];
        xv  = *(const float4*)&X[brow_base];
        gxv = *(const float4*)&gx[brow_base];
    }
    mv = *(const float4*)&M[brow_base];

    // gamma_h[0] -> gh_t[0]
    const int grow = tid >> 5, gcol = tid & 31;
    {
        uint4 g0 = *(const uint4*)&gh[((size_t)(b0 + grow) * Tn + 0) * Hn + gcol * 8];
        *(uint4*)&gh_t[0][grow * 264 + gcol * 8] = g0;
    }
    __syncthreads();

    const f4_t z4 = {0.f, 0.f, 0.f, 0.f};
    float hdc[2][4], zzv[2][4];

    for (int t = 0; t < Tn; ++t) {
        const int cur = t & 1, nxt = cur ^ 1;
        const int tn = (t + 1 < Tn) ? (t + 1) : (Tn - 1);

        // ---- PH1: prefetch issues + A-frag builds ----
        uint4 ghpn = *(const uint4*)&gh[((size_t)(b0 + grow) * Tn + tn) * Hn + gcol * 8];

        bf8_t whz[2][8], whr[2][8];     // z/r hidden-weight streams (L2)
        #pragma unroll
        for (int nt = 0; nt < 2; ++nt)
            #pragma unroll
            for (int kt = 0; kt < 8; ++kt) {
                whz[nt][kt] = LD8(BA(pk + OFF_WH,             2 * w + nt, 8, kt, lane));
                whr[nt][kt] = LD8(BA(pk + OFF_WH + 65536,     2 * w + nt, 8, kt, lane));
            }

        // hd A-frag build (all waves; wave w owns cols [32w, 32w+32))
        {
            const int hr = lane & 15, hc0 = w * 32 + ((lane >> 4) << 3);
            uint4 g4 = *(const uint4*)&gh_t[cur][hr * 264 + hc0];
            float4 h0 = *(const float4*)&sh_h[hr][hc0];
            float4 h1 = *(const float4*)&sh_h[hr][hc0 + 4];
            unsigned int gu[4] = {g4.x, g4.y, g4.z, g4.w};
            float hh[8] = {h0.x, h0.y, h0.z, h0.w, h1.x, h1.y, h1.z, h1.w};
            bf8_t hv;
            #pragma unroll
            for (int i = 0; i < 8; ++i) {
                float gval = bf2f((unsigned short)((gu[i >> 1] >> ((i & 1) * 16)) & 0xffffu));
                hv[i] = (short)f2bf(gval * hh[i]);
            }
            *(bf8_t*)&sA_hd[(w * 64 + lane) * 8] = hv;
        }
        // x_hat frag (lanes<32) / m frag (lanes>=32)
        if (lane < 32) {
            float mm[4] = {mv.x, mv.y, mv.z, mv.w};
            float xx[4] = {xv.x, xv.y, xv.z, xv.w};
            float gg[4] = {gxv.x, gxv.y, gxv.z, gxv.w};
            unsigned int d0, d1;
            float xh[4];
            #pragma unroll
            for (int j = 0; j < 4; ++j) {
                xh[j] = mm[j] * xx[j] + (1.f - mm[j]) * (gg[j] * xp[j] + (1.f - gg[j]) * xb[j]);
                xp[j] = mm[j] * xx[j] + (1.f - mm[j]) * xp[j];
            }
            d0 = (unsigned int)f2bf(xh[0]) | ((unsigned int)f2bf(xh[1]) << 16);
            d1 = (unsigned int)f2bf(xh[2]) | ((unsigned int)f2bf(xh[3]) << 16);
            uint2 dd; dd.x = d0; dd.y = d1;
            *(uint2*)&sA_xh[(kt2 * 64 + fl) * 8 + half * 4] = dd;
        } else {
            unsigned int d0 = (unsigned int)f2bf(mv.x) | ((unsigned int)f2bf(mv.y) << 16);
            unsigned int d1 = (unsigned int)f2bf(mv.z) | ((unsigned int)f2bf(mv.w) << 16);
            uint2 dd; dd.x = d0; dd.y = d1;
            *(uint2*)&sA_m[(kt2 * 64 + fl) * 8 + half * 4] = dd;
        }
        // reissue builder loads for t+1 (full-step lead)
        {
            const size_t ba = brow_base + (size_t)tn * Dn;
            mv = *(const float4*)&M[ba];
            if (lane < 32) {
                xv  = *(const float4*)&X[ba];
                gxv = *(const float4*)&gx[ba];
            }
        }
        __syncthreads();   // bar0

        // ---- PH2: z and r gates ----
        bf8_t wmz[2][2], wmr[2][2];
        #pragma unroll
        for (int nt = 0; nt < 2; ++nt)
            #pragma unroll
            for (int kt = 0; kt < 2; ++kt) {
                wmz[nt][kt] = LD8(BA(pk + OFF_WM,          2 * w + nt, 2, kt, lane));
                wmr[nt][kt] = LD8(BA(pk + OFF_WM + 16384,  2 * w + nt, 2, kt, lane));
            }
        bf8_t xf0 = LD8(&sA_xh[lane * 8]),       xf1 = LD8(&sA_xh[(64 + lane) * 8]);
        bf8_t mf0 = LD8(&sA_m[lane * 8]),        mf1 = LD8(&sA_m[(64 + lane) * 8]);
        bf8_t wxz[2][2], wxr[2][2];
        #pragma unroll
        for (int nt = 0; nt < 2; ++nt)
            #pragma unroll
            for (int kt = 0; kt < 2; ++kt) {
                wxz[nt][kt] = LD8(&sWx[(((size_t)(0 * 16 + 2 * w + nt) * 2 + kt) * 64 + lane) * 8]);
                wxr[nt][kt] = LD8(&sWx[(((size_t)(1 * 16 + 2 * w + nt) * 2 + kt) * 64 + lane) * 8]);
            }
        f4_t aZ[2] = {z4, z4}, aR[2] = {z4, z4};
        #pragma unroll
        for (int kt = 0; kt < 8; ++kt) {
            bf8_t hf = LD8(&sA_hd[(kt * 64 + lane) * 8]);
            aZ[0] = MF(hf, whz[0][kt], aZ[0]); aZ[1] = MF(hf, whz[1][kt], aZ[1]);
            aR[0] = MF(hf, whr[0][kt], aR[0]); aR[1] = MF(hf, whr[1][kt], aR[1]);
        }
        // issue PH3 streams now (whz/whr registers die here)
        bf8_t whh[2][8], wmh[2][2];
        #pragma unroll
        for (int nt = 0; nt < 2; ++nt) {
            #pragma unroll
            for (int kt = 0; kt < 8; ++kt)
                whh[nt][kt] = LD8(BA(pk + OFF_WH + 2 * 65536, 2 * w + nt, 8, kt, lane));
            #pragma unroll
            for (int kt = 0; kt < 2; ++kt)
                wmh[nt][kt] = LD8(BA(pk + OFF_WM + 2 * 16384, 2 * w + nt, 2, kt, lane));
        }
        #pragma unroll
        for (int nt = 0; nt < 2; ++nt) {
            aZ[nt] = MF(xf0, wxz[nt][0], aZ[nt]); aZ[nt] = MF(xf1, wxz[nt][1], aZ[nt]);
            aZ[nt] = MF(mf0, wmz[nt][0], aZ[nt]); aZ[nt] = MF(mf1, wmz[nt][1], aZ[nt]);
            aR[nt] = MF(xf0, wxr[nt][0], aR[nt]); aR[nt] = MF(xf1, wxr[nt][1], aR[nt]);
            aR[nt] = MF(mf0, wmr[nt][0], aR[nt]); aR[nt] = MF(mf1, wmr[nt][1], aR[nt]);
        }
        #pragma unroll
        for (int nt = 0; nt < 2; ++nt) {
            const int col = w * 32 + nt * 16 + c15;
            #pragma unroll
            for (int q = 0; q < 4; ++q) {
                const int r = rowb + q;
                float z  = 1.f / (1.f + __expf(-(aZ[nt][q] + bz[nt])));
                float rr = 1.f / (1.f + __expf(-(aR[nt][q] + brr[nt])));
                float ghc = bf2f(gh_t[cur][r * 264 + col]);
                float hc  = sh_h[r][col];
                float hd  = ghc * hc;
                hdc[nt][q] = hd; zzv[nt][q] = z;
                sA_rhd[(w * 64 + ((col & 31) >> 3) * 16 + r) * 8 + (col & 7)] =
                    (short)f2bf(rr * hd);
            }
        }
        __syncthreads();   // bar1

        // ---- PH3: h_tilde + h update + restage ----
        bf8_t wxh[2][2];
        #pragma unroll
        for (int nt = 0; nt < 2; ++nt)
            #pragma unroll
            for (int kt = 0; kt < 2; ++kt)
                wxh[nt][kt] = LD8(&sWx[(((size_t)(2 * 16 + 2 * w + nt) * 2 + kt) * 64 + lane) * 8]);
        f4_t aH[2] = {z4, z4};
        #pragma unroll
        for (int kt = 0; kt < 8; ++kt) {
            bf8_t rf = LD8(&sA_rhd[(kt * 64 + lane) * 8]);
            aH[0] = MF(rf, whh[0][kt], aH[0]); aH[1] = MF(rf, whh[1][kt], aH[1]);
        }
        #pragma unroll
        for (int nt = 0; nt < 2; ++nt) {
            aH[nt] = MF(xf0, wxh[nt][0], aH[nt]); aH[nt] = MF(xf1, wxh[nt][1], aH[nt]);
            aH[nt] = MF(mf0, wmh[nt][0], aH[nt]); aH[nt] = MF(mf1, wmh[nt][1], aH[nt]);
        }
        #pragma unroll
        for (int nt = 0; nt < 2; ++nt) {
            const int col = w * 32 + nt * 16 + c15;
            #pragma unroll
            for (int q = 0; q < 4; ++q) {
                const int r = rowb + q;
                float pre = aH[nt][q] + bh[nt];
                float a = fabsf(pre), e = __expf(-2.f * a);
                float th = copysignf((1.f - e) / (1.f + e), pre);
                sh_h[r][col] = (1.f - zzv[nt][q]) * hdc[nt][q] + zzv[nt][q] * th;
            }
        }
        *(uint4*)&gh_t[nxt][grow * 264 + gcol * 8] = ghpn;
        __syncthreads();   // end-bar
    }

    // ---- classifier ----
    #pragma unroll
    for (int rr = 0; rr < 2; ++rr) {
        const int row = w * 2 + rr;
        float4 hv = *(const float4*)&sh_h[row][lane * 4];
        float4 wv = *(const float4*)&W_cls[lane * 4];
        float p = hv.x * wv.x + hv.y * wv.y + hv.z * wv.z + hv.w * wv.w;
        #pragma unroll
        for (int o = 32; o > 0; o >>= 1) p += __shfl_down(p, o, 64);
        if (lane == 0) out[b0 + row] = p + b_cls[0];
    }
}

// ---------------------------------------------------------------------------
// Fallback (round-2 kernel, used only if ws_size < WS_NEED)
// ---------------------------------------------------------------------------
__global__ __launch_bounds__(512, 2) void grud_main(
    const float* __restrict__ X, const float* __restrict__ M, const float* __restrict__ Dl,
    const float* __restrict__ x_mean, const float* __restrict__ b_gx,
    const float* __restrict__ b_gh, const float* __restrict__ b_g,
    const float* __restrict__ W_cls, const float* __restrict__ b_cls,
    const short* __restrict__ pk, float* __restrict__ out)
{
    __shared__ float sh_h [BB][Hn];
    __shared__ float sh_xp[BB][Dn];
    __shared__ float sh_x [BB][Dn];
    __shared__ float sh_m [BB][Dn];
    __shared__ short sA_d  [2 * 64 * 8];
    __shared__ short sA_m  [2 * 64 * 8];
    __shared__ short sA_xh [2 * 64 * 8];
    __shared__ short sA_hd [8 * 64 * 8];
    __shared__ short sA_rhd[8 * 64 * 8];
    __shared__ float sh_bgx[Dn], sh_xmean[Dn], sh_bgh[Hn], sh_bg[3][Hn];

    const int tid  = threadIdx.x;
    const int w    = tid >> 6, lane = tid & 63;
    const int b0   = blockIdx.x * BB;
    const int rowb = (lane >> 4) * 4;
    const int c15  = lane & 15;

    for (int i = tid; i < BB * Hn; i += 512) (&sh_h[0][0])[i]  = 0.f;
    for (int i = tid; i < BB * Dn; i += 512) (&sh_xp[0][0])[i] = 0.f;
    if (tid < Dn) { sh_bgx[tid] = b_gx[tid]; sh_xmean[tid] = x_mean[tid]; }
    if (tid < Hn) sh_bgh[tid] = b_gh[tid];
    for (int i = tid; i < 3 * Hn; i += 512) (&sh_bg[0][0])[i] = b_g[i];
    __syncthreads();

    const short* whp  = pk + OFF_WH;
    const short* wxp  = pk + OFF_WX;
    const short* wmp  = pk + OFF_WM;
    const short* wghp = pk + OFF_WGH;
    const short* wgxp = pk + OFF_WGX;

    for (int t = 0; t < Tn; ++t) {
        if (tid < 128) {
            const int kt2 = tid >> 6, lf = tid & 63;
            const int r = lf & 15, db = kt2 * 32 + ((lf >> 4) << 3);
            const float* p = Dl + ((size_t)(b0 + r) * Tn + t) * Dn + db;
            float4 a = *(const float4*)p, b = *(const float4*)(p + 4);
            bf8_t v;
            v[0]=(short)f2bf(a.x); v[1]=(short)f2bf(a.y); v[2]=(short)f2bf(a.z); v[3]=(short)f2bf(a.w);
            v[4]=(short)f2bf(b.x); v[5]=(short)f2bf(b.y); v[6]=(short)f2bf(b.z); v[7]=(short)f2bf(b.w);
            *(bf8_t*)&sA_d[tid * 8] = v;
        } else if (tid < 256) {
            const int s2 = tid - 128;
            const int kt2 = s2 >> 6, lf = s2 & 63;
            const int r = lf & 15, db = kt2 * 32 + ((lf >> 4) << 3);
            const float* p = M + ((size_t)(b0 + r) * Tn + t) * Dn + db;
            float4 a = *(const float4*)p, b = *(const float4*)(p + 4);
            bf8_t v;
            v[0]=(short)f2bf(a.x); v[1]=(short)f2bf(a.y); v[2]=(short)f2bf(a.z); v[3]=(short)f2bf(a.w);
            v[4]=(short)f2bf(b.x); v[5]=(short)f2bf(b.y); v[6]=(short)f2bf(b.z); v[7]=(short)f2bf(b.w);
            *(bf8_t*)&sA_m[s2 * 8] = v;
        } else {
            const int s2 = tid - 256, r = s2 >> 4, seg = (s2 & 15) * 4;
            const size_t off = ((size_t)(b0 + r) * Tn + t) * Dn + seg;
            *(float4*)&sh_x[r][seg] = *(const float4*)(X + off);
            *(float4*)&sh_m[r][seg] = *(const float4*)(M + off);
        }
        __syncthreads();

        bf8_t df0 = *(const bf8_t*)&sA_d[(0 * 64 + lane) * 8];
        bf8_t df1 = *(const bf8_t*)&sA_d[(1 * 64 + lane) * 8];
        f4_t accG0 = {0.f,0.f,0.f,0.f}, accG1 = {0.f,0.f,0.f,0.f};
        accG0 = MFp(df0, BA(wghp, 2*w+0, 2, 0, lane), accG0);
        accG0 = MFp(df1, BA(wghp, 2*w+0, 2, 1, lane), accG0);
        accG1 = MFp(df0, BA(wghp, 2*w+1, 2, 0, lane), accG1);
        accG1 = MFp(df1, BA(wghp, 2*w+1, 2, 1, lane), accG1);
        if (w < 4) {
            f4_t aGx = {0.f,0.f,0.f,0.f};
            aGx = MFp(df0, BA(wgxp, w, 2, 0, lane), aGx);
            aGx = MFp(df1, BA(wgxp, w, 2, 1, lane), aGx);
            const int col = w * 16 + c15;
            #pragma unroll
            for (int q = 0; q < 4; ++q) {
                const int r = rowb + q;
                float gxs = __expf(-fmaxf(aGx[q] + sh_bgx[col], 0.f));
                float mvs = sh_m[r][col], xvs = sh_x[r][col], xpv = sh_xp[r][col];
                float xh  = mvs * xvs + (1.f - mvs) * (gxs * xpv + (1.f - gxs) * sh_xmean[col]);
                sh_xp[r][col] = mvs * xvs + (1.f - mvs) * xpv;
                sA_xh[((col >> 5) * 64 + (((col & 31) >> 3) << 4) + r) * 8 + (col & 7)]
                    = (short)f2bf(xh);
            }
        }
        __syncthreads();

        bf8_t xf0 = *(const bf8_t*)&sA_xh[(0 * 64 + lane) * 8];
        bf8_t xf1 = *(const bf8_t*)&sA_xh[(1 * 64 + lane) * 8];
        bf8_t mf0 = *(const bf8_t*)&sA_m [(0 * 64 + lane) * 8];
        bf8_t mf1 = *(const bf8_t*)&sA_m [(1 * 64 + lane) * 8];
        f4_t accP[3][2];
        #pragma unroll
        for (int g = 0; g < 3; ++g) {
            const short* bx = wxp + (size_t)g * 16384;
            const short* bm = wmp + (size_t)g * 16384;
            #pragma unroll
            for (int nt = 0; nt < 2; ++nt) {
                const int ntG = 2 * w + nt;
                f4_t a = {0.f,0.f,0.f,0.f};
                a = MFp(xf0, BA(bx, ntG, 2, 0, lane), a);
                a = MFp(xf1, BA(bx, ntG, 2, 1, lane), a);
                a = MFp(mf0, BA(bm, ntG, 2, 0, lane), a);
                a = MFp(mf1, BA(bm, ntG, 2, 1, lane), a);
                accP[g][nt] = a;
            }
        }
        float hd2[2][4];
        #pragma unroll
        for (int nt = 0; nt < 2; ++nt) {
            const f4_t aG = nt ? accG1 : accG0;
            const int col = w * 32 + nt * 16 + c15;
            #pragma unroll
            for (int q = 0; q < 4; ++q) {
                const int r = rowb + q;
                float gh2 = __expf(-fmaxf(aG[q] + sh_bgh[col], 0.f));
                float hdv = gh2 * sh_h[r][col];
                hd2[nt][q] = hdv;
                sA_hd[((size_t)w * 64 + (((col & 31) >> 3) << 4) + r) * 8 + (col & 7)]
                    = (short)f2bf(hdv);
            }
        }
        __syncthreads();

        f4_t accZ[2] = {accP[0][0], accP[0][1]};
        f4_t accR[2] = {accP[1][0], accP[1][1]};
        #pragma unroll
        for (int kt = 0; kt < 8; ++kt) {
            bf8_t hf = *(const bf8_t*)&sA_hd[(kt * 64 + lane) * 8];
            #pragma unroll
            for (int nt = 0; nt < 2; ++nt) {
                const int ntG = 2 * w + nt;
                accZ[nt] = MFp(hf, BA(whp + 0 * 65536, ntG, 8, kt, lane), accZ[nt]);
                accR[nt] = MFp(hf, BA(whp + 1 * 65536, ntG, 8, kt, lane), accR[nt]);
            }
        }
        float zz2[2][4];
        #pragma unroll
        for (int nt = 0; nt < 2; ++nt) {
            const int col = w * 32 + nt * 16 + c15;
            #pragma unroll
            for (int q = 0; q < 4; ++q) {
                const int r = rowb + q;
                float z  = 1.f / (1.f + __expf(-(accZ[nt][q] + sh_bg[0][col])));
                float rv = 1.f / (1.f + __expf(-(accR[nt][q] + sh_bg[1][col])));
                zz2[nt][q] = z;
                sA_rhd[((size_t)w * 64 + (((col & 31) >> 3) << 4) + r) * 8 + (col & 7)]
                    = (short)f2bf(rv * hd2[nt][q]);
            }
        }
        __syncthreads();

        f4_t accH[2] = {accP[2][0], accP[2][1]};
        #pragma unroll
        for (int kt = 0; kt < 8; ++kt) {
            bf8_t hf = *(const bf8_t*)&sA_rhd[(kt * 64 + lane) * 8];
            #pragma unroll
            for (int nt = 0; nt < 2; ++nt)
                accH[nt] = MFp(hf, BA(whp + 2 * 65536, 2 * w + nt, 8, kt, lane), accH[nt]);
        }
        #pragma unroll
        for (int nt = 0; nt < 2; ++nt) {
            const int col = w * 32 + nt * 16 + c15;
            #pragma unroll
            for (int q = 0; q < 4; ++q) {
                const int r = rowb + q;
                float pre = accH[nt][q] + sh_bg[2][col];
                float a = fabsf(pre), e = __expf(-2.f * a);
                float th = copysignf((1.f - e) / (1.f + e), pre);
                sh_h[r][col] = (1.f - zz2[nt][q]) * hd2[nt][q] + zz2[nt][q] * th;
            }
        }
        __syncthreads();
    }

    if (tid < BB) {
        float s2 = 0.f;
        for (int k = 0; k < Hn; ++k) s2 = fmaf(sh_h[tid][k], W_cls[k], s2);
        out[b0 + tid] = s2 + b_cls[0];
    }
}

extern "C" void kernel_launch(void* const* d_in, const int* in_sizes, int n_in,
                              void* d_out, int out_size, void* d_ws, size_t ws_size,
                              hipStream_t stream) {
    const float* X      = (const float*)d_in[0];
    const float* M      = (const float*)d_in[1];
    const float* Dl     = (const float*)d_in[2];
    const float* x_mean = (const float*)d_in[3];
    const float* W_gx   = (const float*)d_in[4];
    const float* b_gx   = (const float*)d_in[5];
    const float* W_gh   = (const float*)d_in[6];
    const float* b_gh   = (const float*)d_in[7];
    const float* W_x    = (const float*)d_in[8];
    const float* W_h    = (const float*)d_in[9];
    const float* W_m    = (const float*)d_in[10];
    const float* b_g    = (const float*)d_in[11];
    const float* W_cls  = (const float*)d_in[12];
    const float* b_cls  = (const float*)d_in[13];
    float* out = (float*)d_out;
    short* pk  = (short*)d_ws;

    hipLaunchKernelGGL(pack_weights, dim3((PACK_SLOTS + 255) / 256), dim3(256), 0, stream,
                       W_gx, W_gh, W_x, W_h, W_m, pk);

    if (ws_size >= WS_NEED) {
        float* gxbuf = (float*)((char*)d_ws + GX_OFF);
        unsigned short* ghbuf = (unsigned short*)((char*)d_ws + GH_OFF);
        hipLaunchKernelGGL(grud_prepass, dim3(NBLK * Tn), dim3(256), 0, stream,
                           Dl, b_gx, b_gh, pk, gxbuf, ghbuf);
        hipLaunchKernelGGL(grud_rec, dim3(NBLK), dim3(512), 0, stream,
                           X, M, x_mean, b_g, W_cls, b_cls, pk, gxbuf, ghbuf, out);
    } else {
        hipLaunchKernelGGL(grud_main, dim3(NBLK), dim3(512), 0, stream,
                           X, M, Dl, x_mean, b_gx, b_gh, b_g, W_cls, b_cls, pk, out);
    }
}

// Round 4
// 2317.710 us; speedup vs baseline: 2.6220x; 1.0500x over previous
//
#include <hip/hip_runtime.h>

// GRU-D, round 4.
// pack_weights -> prepass (gamma_x f32, gamma_h bf16) -> grud_rec4.
// grud_rec4: 32 blocks x 512 thr, __launch_bounds__(512,2) => 256 VGPR cap.
//   W_h[0], W_h[2] register-resident (128 VGPR, loaded once before t-loop).
//   W_h[1] LDS-resident (128 KB). W_x/W_m streamed from L2 (24 frags/step,
//   issued a phase early). h-state bf16 in LDS; gamma_h loaded per-thread
//   in both A-frag and C/D layouts, prefetched one step ahead.

constexpr int Bn = 512, Tn = 256, Dn = 64, Hn = 256;
constexpr int BB = 16, NBLK = Bn / BB;   // 32 blocks

typedef __attribute__((ext_vector_type(8))) short bf8_t;   // 8 x bf16 bits
typedef __attribute__((ext_vector_type(4))) float f4_t;    // MFMA accumulator

// packed-weight region offsets in shorts
constexpr size_t OFF_WH  = 0;        // 3 * 16nt * 8kt * 64 * 8
constexpr size_t OFF_WX  = 196608;   // 3 * 16nt * 2kt * 64 * 8
constexpr size_t OFF_WM  = 245760;
constexpr size_t OFF_WGH = 294912;   // 16nt * 2kt * 64 * 8
constexpr size_t OFF_WGX = 311296;   // 4nt * 2kt * 64 * 8
constexpr int    PACK_SLOTS = 39424;

// workspace layout (bytes) — identical to round 3 (proven available)
constexpr size_t GX_OFF  = (size_t)1 << 20;                      // gamma_x f32 [B][T][D]
constexpr size_t GH_OFF  = GX_OFF + (size_t)Bn * Tn * Dn * 4;    // gamma_h bf16 [B][T][H]
constexpr size_t WS_NEED = GH_OFF + (size_t)Bn * Tn * Hn * 2;

__device__ __forceinline__ unsigned short f2bf(float x) {
    union { float f; unsigned int u; } v; v.f = x;
    unsigned int r = (v.u + 0x7fffu + ((v.u >> 16) & 1u)) >> 16;   // RNE
    return (unsigned short)r;
}
__device__ __forceinline__ float bf2f(unsigned short u) {
    union { unsigned int i; float f; } v; v.i = ((unsigned int)u) << 16; return v.f;
}
__device__ __forceinline__ bf8_t LD8(const short* p) { return *(const bf8_t*)p; }

__device__ __forceinline__ f4_t MF(bf8_t a, bf8_t b, f4_t c) {
    return __builtin_amdgcn_mfma_f32_16x16x32_bf16(a, b, c, 0, 0, 0);
}
__device__ __forceinline__ f4_t MFp(bf8_t a, const short* bp, f4_t c) {
    return MF(a, LD8(bp), c);
}
__device__ __forceinline__ const short* BA(const short* p, int ntG, int KT, int kt, int lane) {
    return p + (((size_t)ntG * KT + kt) * 64 + lane) * 8;
}

// ---------------------------------------------------------------------------
// pack_weights (unchanged)
// ---------------------------------------------------------------------------
__global__ __launch_bounds__(256) void pack_weights(
    const float* __restrict__ W_gx, const float* __restrict__ W_gh,
    const float* __restrict__ W_x,  const float* __restrict__ W_h,
    const float* __restrict__ W_m,  short* __restrict__ out)
{
    const int slot = blockIdx.x * 256 + threadIdx.x;
    if (slot >= PACK_SLOTS) return;

    const float* w; int ldn, l, kt, j, kbase;
    if (slot < 24576) {
        int g = slot >> 13, rem = slot & 8191;
        int ntG = rem >> 9, r2 = rem & 511;
        kt = r2 >> 6; l = r2 & 63;
        j = ntG * 16 + (l & 15);
        w = W_h + (size_t)g * Hn * Hn; ldn = Hn;
    } else if (slot < 30720) {
        int s = slot - 24576;
        int g = s >> 11, rem = s & 2047;
        int ntG = rem >> 7, r2 = rem & 127;
        kt = r2 >> 6; l = r2 & 63;
        j = ntG * 16 + (l & 15);
        w = W_x + (size_t)g * Dn * Hn; ldn = Hn;
    } else if (slot < 36864) {
        int s = slot - 30720;
        int g = s >> 11, rem = s & 2047;
        int ntG = rem >> 7, r2 = rem & 127;
        kt = r2 >> 6; l = r2 & 63;
        j = ntG * 16 + (l & 15);
        w = W_m + (size_t)g * Dn * Hn; ldn = Hn;
    } else if (slot < 38912) {
        int s = slot - 36864;
        int ntG = s >> 7, r2 = s & 127;
        kt = r2 >> 6; l = r2 & 63;
        j = ntG * 16 + (l & 15);
        w = W_gh; ldn = Hn;
    } else {
        int s = slot - 38912;
        int ntG = s >> 7, r2 = s & 127;
        kt = r2 >> 6; l = r2 & 63;
        j = ntG * 16 + (l & 15);
        w = W_gx; ldn = Dn;
    }
    kbase = kt * 32 + ((l >> 4) << 3);
    bf8_t v;
    #pragma unroll
    for (int i = 0; i < 8; ++i)
        v[i] = (short)f2bf(w[(size_t)(kbase + i) * ldn + j]);
    *(bf8_t*)&out[(size_t)slot * 8] = v;
}

// ---------------------------------------------------------------------------
// prepass (unchanged): gamma_x f32, gamma_h bf16 for all (b,t)
// ---------------------------------------------------------------------------
__global__ __launch_bounds__(256) void grud_prepass(
    const float* __restrict__ Dl, const float* __restrict__ b_gx,
    const float* __restrict__ b_gh, const short* __restrict__ pk,
    float* __restrict__ gx, unsigned short* __restrict__ gh)
{
    __shared__ short sDf[2 * 64 * 8];
    const int tid = threadIdx.x, w = tid >> 6, lane = tid & 63;
    const int bt = blockIdx.x >> 8, t = blockIdx.x & 255;
    const int b0 = bt * 16;
    const int c15 = lane & 15, rowb = (lane >> 4) * 4;

    if (w < 2) {
        const int row = lane & 15, cb = w * 32 + ((lane >> 4) << 3);
        const float* p = Dl + ((size_t)(b0 + row) * Tn + t) * Dn + cb;
        float4 a = *(const float4*)p, b = *(const float4*)(p + 4);
        bf8_t v;
        v[0]=(short)f2bf(a.x); v[1]=(short)f2bf(a.y); v[2]=(short)f2bf(a.z); v[3]=(short)f2bf(a.w);
        v[4]=(short)f2bf(b.x); v[5]=(short)f2bf(b.y); v[6]=(short)f2bf(b.z); v[7]=(short)f2bf(b.w);
        *(bf8_t*)&sDf[(w * 64 + lane) * 8] = v;
    }
    __syncthreads();
    bf8_t df0 = *(const bf8_t*)&sDf[lane * 8];
    bf8_t df1 = *(const bf8_t*)&sDf[(64 + lane) * 8];

    #pragma unroll
    for (int i = 0; i < 4; ++i) {
        const int ntG = 4 * w + i;
        f4_t acc = {0.f, 0.f, 0.f, 0.f};
        acc = MFp(df0, BA(pk + OFF_WGH, ntG, 2, 0, lane), acc);
        acc = MFp(df1, BA(pk + OFF_WGH, ntG, 2, 1, lane), acc);
        const int col = ntG * 16 + c15;
        const float bb = b_gh[col];
        #pragma unroll
        for (int q = 0; q < 4; ++q) {
            const int r = rowb + q;
            gh[((size_t)(b0 + r) * Tn + t) * Hn + col] =
                f2bf(__expf(-fmaxf(acc[q] + bb, 0.f)));
        }
    }
    {
        f4_t acc = {0.f, 0.f, 0.f, 0.f};
        acc = MFp(df0, BA(pk + OFF_WGX, w, 2, 0, lane), acc);
        acc = MFp(df1, BA(pk + OFF_WGX, w, 2, 1, lane), acc);
        const int col = w * 16 + c15;
        const float bb = b_gx[col];
        #pragma unroll
        for (int q = 0; q < 4; ++q) {
            const int r = rowb + q;
            gx[((size_t)(b0 + r) * Tn + t) * Dn + col] =
                __expf(-fmaxf(acc[q] + bb, 0.f));
        }
    }
}

// ---------------------------------------------------------------------------
// grud_rec4: fused recurrence, W_h[0]/W_h[2] in registers, W_h[1] in LDS.
// ---------------------------------------------------------------------------
__global__ __launch_bounds__(512, 2) void grud_rec4(
    const float* __restrict__ X, const float* __restrict__ M,
    const float* __restrict__ x_mean, const float* __restrict__ b_g,
    const float* __restrict__ W_cls, const float* __restrict__ b_cls,
    const short* __restrict__ pk, const float* __restrict__ gx,
    const unsigned short* __restrict__ gh, float* __restrict__ out)
{
    __shared__ short sWh1[16 * 8 * 64 * 8];      // 131072 B : W_h[1] B-frags
    __shared__ unsigned short sh_hb[16][264];    //   8448 B : h state (bf16, padded)
    __shared__ short sA_xh[2 * 64 * 8];          //   2048 B
    __shared__ short sA_m [2 * 64 * 8];          //   2048 B
    __shared__ short sA_hd[8 * 64 * 8];          //   8192 B
    __shared__ short sA_rhd[8 * 64 * 8];         //   8192 B   => total 160000 B

    const int tid = threadIdx.x, w = tid >> 6, lane = tid & 63;
    const int c15 = lane & 15, rowb = (lane >> 4) * 4;
    const int b0 = blockIdx.x * BB;

    // ---- resident weights: W_h[0] (z) and W_h[2] (h~): 32 frags = 128 VGPR ----
    bf8_t whz[2][8], whh[2][8];
    #pragma unroll
    for (int nt = 0; nt < 2; ++nt)
        #pragma unroll
        for (int kt = 0; kt < 8; ++kt) {
            whz[nt][kt] = LD8(BA(pk + OFF_WH,             2 * w + nt, 8, kt, lane));
            whh[nt][kt] = LD8(BA(pk + OFF_WH + 2 * 65536, 2 * w + nt, 8, kt, lane));
        }
    // ---- stage W_h[1] into LDS ----
    for (int c = tid; c < 8192; c += 512)
        *(uint4*)&sWh1[c * 8] = *(const uint4*)&pk[OFF_WH + 65536 + (size_t)c * 8];
    // ---- zero h state ----
    for (int i = tid; i < 16 * 264; i += 512) (&sh_hb[0][0])[i] = 0;

    // ---- biases ----
    const float bz[2] = { b_g[0 * Hn + w * 32 + c15], b_g[0 * Hn + w * 32 + 16 + c15] };
    const float brr[2]= { b_g[1 * Hn + w * 32 + c15], b_g[1 * Hn + w * 32 + 16 + c15] };
    const float bh[2] = { b_g[2 * Hn + w * 32 + c15], b_g[2 * Hn + w * 32 + 16 + c15] };

    // ---- builder mapping (x-side A-frags), round-3 proven ----
    const int s    = w * 32 + (lane & 31);
    const int kt2  = s >> 7, fl = (s >> 1) & 63, half = s & 1;
    const int brow = fl & 15, bcol = kt2 * 32 + ((fl >> 4) << 3) + half * 4;
    const size_t brow_base = ((size_t)(b0 + brow) * Tn) * Dn + bcol;

    float xb[4] = {0.f, 0.f, 0.f, 0.f};
    float xp[4] = {0.f, 0.f, 0.f, 0.f};
    float4 mv, xv = {0,0,0,0}, gxv = {0,0,0,0};
    if (lane < 32) {
        xb[0]=x_mean[bcol]; xb[1]=x_mean[bcol+1]; xb[2]=x_mean[bcol+2]; xb[3]=x_mean[bcol+3];
        xv  = *(const float4*)&X[brow_base];
        gxv = *(const float4*)&gx[brow_base];
    }
    mv = *(const float4*)&M[brow_base];

    // ---- gamma_h prefetch state ----
    const size_t ghA_base  = ((size_t)(b0 + (lane & 15)) * Tn) * Hn + w * 32 + ((lane >> 4) << 3);
    uint4 gha = *(const uint4*)&gh[ghA_base];            // t = 0, A-layout (8 bf16)
    unsigned short ghcd[2][4];                           // t = 0, C/D layout
    #pragma unroll
    for (int nt = 0; nt < 2; ++nt)
        #pragma unroll
        for (int q = 0; q < 4; ++q)
            ghcd[nt][q] = gh[((size_t)(b0 + rowb + q) * Tn) * Hn + w * 32 + nt * 16 + c15];

    float h_cd[2][4] = {{0.f,0.f,0.f,0.f},{0.f,0.f,0.f,0.f}};
    float hd_cd[2][4], zz[2][4];
    const f4_t z4 = {0.f, 0.f, 0.f, 0.f};
    __syncthreads();

    for (int t = 0; t < Tn; ++t) {
        const int tn = (t + 1 < Tn) ? (t + 1) : (Tn - 1);

        // ================= PH1: A-frag builds + prefetch issues =================
        // hd A-frag: read h (bf16, A-layout) from LDS, multiply gamma_h(t)
        {
            uint4 hA = *(const uint4*)&sh_hb[lane & 15][w * 32 + ((lane >> 4) << 3)];
            unsigned int ga[4] = {gha.x, gha.y, gha.z, gha.w};
            unsigned int ha[4] = {hA.x, hA.y, hA.z, hA.w};
            bf8_t hv;
            #pragma unroll
            for (int i = 0; i < 8; ++i) {
                float gf = bf2f((unsigned short)((ga[i >> 1] >> ((i & 1) * 16)) & 0xffffu));
                float hf = bf2f((unsigned short)((ha[i >> 1] >> ((i & 1) * 16)) & 0xffffu));
                hv[i] = (short)f2bf(gf * hf);
            }
            *(bf8_t*)&sA_hd[(w * 64 + lane) * 8] = hv;
        }
        // hd in C/D layout (registers, f32-precise h)
        #pragma unroll
        for (int nt = 0; nt < 2; ++nt)
            #pragma unroll
            for (int q = 0; q < 4; ++q)
                hd_cd[nt][q] = bf2f(ghcd[nt][q]) * h_cd[nt][q];

        // x-side frags: x_hat (lanes<32) / m (lanes>=32)
        if (lane < 32) {
            float mm[4] = {mv.x, mv.y, mv.z, mv.w};
            float xx[4] = {xv.x, xv.y, xv.z, xv.w};
            float gg[4] = {gxv.x, gxv.y, gxv.z, gxv.w};
            float xh[4];
            #pragma unroll
            for (int j = 0; j < 4; ++j) {
                xh[j] = mm[j] * xx[j] + (1.f - mm[j]) * (gg[j] * xp[j] + (1.f - gg[j]) * xb[j]);
                xp[j] = mm[j] * xx[j] + (1.f - mm[j]) * xp[j];
            }
            uint2 dd;
            dd.x = (unsigned int)f2bf(xh[0]) | ((unsigned int)f2bf(xh[1]) << 16);
            dd.y = (unsigned int)f2bf(xh[2]) | ((unsigned int)f2bf(xh[3]) << 16);
            *(uint2*)&sA_xh[(kt2 * 64 + fl) * 8 + half * 4] = dd;
        } else {
            uint2 dd;
            dd.x = (unsigned int)f2bf(mv.x) | ((unsigned int)f2bf(mv.y) << 16);
            dd.y = (unsigned int)f2bf(mv.z) | ((unsigned int)f2bf(mv.w) << 16);
            *(uint2*)&sA_m[(kt2 * 64 + fl) * 8 + half * 4] = dd;
        }
        // prefetch t+1 streams (consumed next step)
        {
            const size_t ba = brow_base + (size_t)tn * Dn;
            mv = *(const float4*)&M[ba];
            if (lane < 32) {
                xv  = *(const float4*)&X[ba];
                gxv = *(const float4*)&gx[ba];
            }
            gha = *(const uint4*)&gh[ghA_base + (size_t)tn * Hn];
            #pragma unroll
            for (int nt = 0; nt < 2; ++nt)
                #pragma unroll
                for (int q = 0; q < 4; ++q)
                    ghcd[nt][q] = gh[((size_t)(b0 + rowb + q) * Tn + tn) * Hn + w * 32 + nt * 16 + c15];
        }
        __syncthreads();   // bar0

        // ================= PH2: z and r gates =================
        // streamed x-side weights (L2-hot), issued before the MFMA chain
        bf8_t wxz[2][2], wxr[2][2], wmz[2][2], wmr[2][2];
        #pragma unroll
        for (int nt = 0; nt < 2; ++nt)
            #pragma unroll
            for (int kt = 0; kt < 2; ++kt) {
                wxz[nt][kt] = LD8(BA(pk + OFF_WX,         2 * w + nt, 2, kt, lane));
                wxr[nt][kt] = LD8(BA(pk + OFF_WX + 16384, 2 * w + nt, 2, kt, lane));
                wmz[nt][kt] = LD8(BA(pk + OFF_WM,         2 * w + nt, 2, kt, lane));
                wmr[nt][kt] = LD8(BA(pk + OFF_WM + 16384, 2 * w + nt, 2, kt, lane));
            }
        bf8_t xf0 = LD8(&sA_xh[lane * 8]), xf1 = LD8(&sA_xh[(64 + lane) * 8]);
        bf8_t mf0 = LD8(&sA_m [lane * 8]), mf1 = LD8(&sA_m [(64 + lane) * 8]);

        f4_t aZ[2] = {z4, z4}, aR[2] = {z4, z4};
        #pragma unroll
        for (int kt = 0; kt < 8; ++kt) {
            bf8_t hf  = LD8(&sA_hd[(kt * 64 + lane) * 8]);
            bf8_t wr0 = LD8(&sWh1[((2 * w + 0) * 8 + kt) * 512 + lane * 8]);
            bf8_t wr1 = LD8(&sWh1[((2 * w + 1) * 8 + kt) * 512 + lane * 8]);
            aZ[0] = MF(hf, whz[0][kt], aZ[0]);
            aZ[1] = MF(hf, whz[1][kt], aZ[1]);
            aR[0] = MF(hf, wr0, aR[0]);
            aR[1] = MF(hf, wr1, aR[1]);
        }
        #pragma unroll
        for (int nt = 0; nt < 2; ++nt) {
            aZ[nt] = MF(xf0, wxz[nt][0], aZ[nt]); aZ[nt] = MF(xf1, wxz[nt][1], aZ[nt]);
            aZ[nt] = MF(mf0, wmz[nt][0], aZ[nt]); aZ[nt] = MF(mf1, wmz[nt][1], aZ[nt]);
            aR[nt] = MF(xf0, wxr[nt][0], aR[nt]); aR[nt] = MF(xf1, wxr[nt][1], aR[nt]);
            aR[nt] = MF(mf0, wmr[nt][0], aR[nt]); aR[nt] = MF(mf1, wmr[nt][1], aR[nt]);
        }
        // issue PH3 streamed weights now (~one epilogue+barrier of lead)
        bf8_t wxh[2][2], wmh[2][2];
        #pragma unroll
        for (int nt = 0; nt < 2; ++nt)
            #pragma unroll
            for (int kt = 0; kt < 2; ++kt) {
                wxh[nt][kt] = LD8(BA(pk + OFF_WX + 32768, 2 * w + nt, 2, kt, lane));
                wmh[nt][kt] = LD8(BA(pk + OFF_WM + 32768, 2 * w + nt, 2, kt, lane));
            }
        // epilogue: z, r, write r*hd frag
        #pragma unroll
        for (int nt = 0; nt < 2; ++nt) {
            const int col = w * 32 + nt * 16 + c15;
            #pragma unroll
            for (int q = 0; q < 4; ++q) {
                const int r = rowb + q;
                float z  = 1.f / (1.f + __expf(-(aZ[nt][q] + bz[nt])));
                float rr = 1.f / (1.f + __expf(-(aR[nt][q] + brr[nt])));
                zz[nt][q] = z;
                sA_rhd[(w * 64 + ((col & 31) >> 3) * 16 + r) * 8 + (col & 7)] =
                    (short)f2bf(rr * hd_cd[nt][q]);
            }
        }
        __syncthreads();   // bar1

        // ================= PH3: h_tilde + h update =================
        f4_t aH[2] = {z4, z4};
        #pragma unroll
        for (int kt = 0; kt < 8; ++kt) {
            bf8_t rf = LD8(&sA_rhd[(kt * 64 + lane) * 8]);
            aH[0] = MF(rf, whh[0][kt], aH[0]);
            aH[1] = MF(rf, whh[1][kt], aH[1]);
        }
        #pragma unroll
        for (int nt = 0; nt < 2; ++nt) {
            aH[nt] = MF(xf0, wxh[nt][0], aH[nt]); aH[nt] = MF(xf1, wxh[nt][1], aH[nt]);
            aH[nt] = MF(mf0, wmh[nt][0], aH[nt]); aH[nt] = MF(mf1, wmh[nt][1], aH[nt]);
        }
        #pragma unroll
        for (int nt = 0; nt < 2; ++nt) {
            const int col = w * 32 + nt * 16 + c15;
            #pragma unroll
            for (int q = 0; q < 4; ++q) {
                const int r = rowb + q;
                float pre = aH[nt][q] + bh[nt];
                float a = fabsf(pre), e = __expf(-2.f * a);
                float th = copysignf((1.f - e) / (1.f + e), pre);
                float hn = (1.f - zz[nt][q]) * hd_cd[nt][q] + zz[nt][q] * th;
                h_cd[nt][q] = hn;
                sh_hb[r][col] = f2bf(hn);
            }
        }
        __syncthreads();   // bar2
    }

    // ---- classifier ----
    #pragma unroll
    for (int rr = 0; rr < 2; ++rr) {
        const int row = w * 2 + rr;
        ushort4 hb = *(const ushort4*)&sh_hb[row][lane * 4];
        float4 wv  = *(const float4*)&W_cls[lane * 4];
        float p = bf2f(hb.x) * wv.x + bf2f(hb.y) * wv.y +
                  bf2f(hb.z) * wv.z + bf2f(hb.w) * wv.w;
        #pragma unroll
        for (int o = 32; o > 0; o >>= 1) p += __shfl_down(p, o, 64);
        if (lane == 0) out[b0 + row] = p + b_cls[0];
    }
}

// ---------------------------------------------------------------------------
// Fallback (round-2 kernel; used only if ws_size < WS_NEED)
// ---------------------------------------------------------------------------
__global__ __launch_bounds__(512, 2) void grud_main(
    const float* __restrict__ X, const float* __restrict__ M, const float* __restrict__ Dl,
    const float* __restrict__ x_mean, const float* __restrict__ b_gx,
    const float* __restrict__ b_gh, const float* __restrict__ b_g,
    const float* __restrict__ W_cls, const float* __restrict__ b_cls,
    const short* __restrict__ pk, float* __restrict__ out)
{
    __shared__ float sh_h [BB][Hn];
    __shared__ float sh_xp[BB][Dn];
    __shared__ float sh_x [BB][Dn];
    __shared__ float sh_m [BB][Dn];
    __shared__ short sA_d  [2 * 64 * 8];
    __shared__ short sA_m  [2 * 64 * 8];
    __shared__ short sA_xh [2 * 64 * 8];
    __shared__ short sA_hd [8 * 64 * 8];
    __shared__ short sA_rhd[8 * 64 * 8];
    __shared__ float sh_bgx[Dn], sh_xmean[Dn], sh_bgh[Hn], sh_bg[3][Hn];

    const int tid  = threadIdx.x;
    const int w    = tid >> 6, lane = tid & 63;
    const int b0   = blockIdx.x * BB;
    const int rowb = (lane >> 4) * 4;
    const int c15  = lane & 15;

    for (int i = tid; i < BB * Hn; i += 512) (&sh_h[0][0])[i]  = 0.f;
    for (int i = tid; i < BB * Dn; i += 512) (&sh_xp[0][0])[i] = 0.f;
    if (tid < Dn) { sh_bgx[tid] = b_gx[tid]; sh_xmean[tid] = x_mean[tid]; }
    if (tid < Hn) sh_bgh[tid] = b_gh[tid];
    for (int i = tid; i < 3 * Hn; i += 512) (&sh_bg[0][0])[i] = b_g[i];
    __syncthreads();

    const short* whp  = pk + OFF_WH;
    const short* wxp  = pk + OFF_WX;
    const short* wmp  = pk + OFF_WM;
    const short* wghp = pk + OFF_WGH;
    const short* wgxp = pk + OFF_WGX;

    for (int t = 0; t < Tn; ++t) {
        if (tid < 128) {
            const int kt2 = tid >> 6, lf = tid & 63;
            const int r = lf & 15, db = kt2 * 32 + ((lf >> 4) << 3);
            const float* p = Dl + ((size_t)(b0 + r) * Tn + t) * Dn + db;
            float4 a = *(const float4*)p, b = *(const float4*)(p + 4);
            bf8_t v;
            v[0]=(short)f2bf(a.x); v[1]=(short)f2bf(a.y); v[2]=(short)f2bf(a.z); v[3]=(short)f2bf(a.w);
            v[4]=(short)f2bf(b.x); v[5]=(short)f2bf(b.y); v[6]=(short)f2bf(b.z); v[7]=(short)f2bf(b.w);
            *(bf8_t*)&sA_d[tid * 8] = v;
        } else if (tid < 256) {
            const int s2 = tid - 128;
            const int kt2 = s2 >> 6, lf = s2 & 63;
            const int r = lf & 15, db = kt2 * 32 + ((lf >> 4) << 3);
            const float* p = M + ((size_t)(b0 + r) * Tn + t) * Dn + db;
            float4 a = *(const float4*)p, b = *(const float4*)(p + 4);
            bf8_t v;
            v[0]=(short)f2bf(a.x); v[1]=(short)f2bf(a.y); v[2]=(short)f2bf(a.z); v[3]=(short)f2bf(a.w);
            v[4]=(short)f2bf(b.x); v[5]=(short)f2bf(b.y); v[6]=(short)f2bf(b.z); v[7]=(short)f2bf(b.w);
            *(bf8_t*)&sA_m[s2 * 8] = v;
        } else {
            const int s2 = tid - 256, r = s2 >> 4, seg = (s2 & 15) * 4;
            const size_t off = ((size_t)(b0 + r) * Tn + t) * Dn + seg;
            *(float4*)&sh_x[r][seg] = *(const float4*)(X + off);
            *(float4*)&sh_m[r][seg] = *(const float4*)(M + off);
        }
        __syncthreads();

        bf8_t df0 = *(const bf8_t*)&sA_d[(0 * 64 + lane) * 8];
        bf8_t df1 = *(const bf8_t*)&sA_d[(1 * 64 + lane) * 8];
        f4_t accG0 = {0.f,0.f,0.f,0.f}, accG1 = {0.f,0.f,0.f,0.f};
        accG0 = MFp(df0, BA(wghp, 2*w+0, 2, 0, lane), accG0);
        accG0 = MFp(df1, BA(wghp, 2*w+0, 2, 1, lane), accG0);
        accG1 = MFp(df0, BA(wghp, 2*w+1, 2, 0, lane), accG1);
        accG1 = MFp(df1, BA(wghp, 2*w+1, 2, 1, lane), accG1);
        if (w < 4) {
            f4_t aGx = {0.f,0.f,0.f,0.f};
            aGx = MFp(df0, BA(wgxp, w, 2, 0, lane), aGx);
            aGx = MFp(df1, BA(wgxp, w, 2, 1, lane), aGx);
            const int col = w * 16 + c15;
            #pragma unroll
            for (int q = 0; q < 4; ++q) {
                const int r = rowb + q;
                float gxs = __expf(-fmaxf(aGx[q] + sh_bgx[col], 0.f));
                float mvs = sh_m[r][col], xvs = sh_x[r][col], xpv = sh_xp[r][col];
                float xh  = mvs * xvs + (1.f - mvs) * (gxs * xpv + (1.f - gxs) * sh_xmean[col]);
                sh_xp[r][col] = mvs * xvs + (1.f - mvs) * xpv;
                sA_xh[((col >> 5) * 64 + (((col & 31) >> 3) << 4) + r) * 8 + (col & 7)]
                    = (short)f2bf(xh);
            }
        }
        __syncthreads();

        bf8_t xf0 = *(const bf8_t*)&sA_xh[(0 * 64 + lane) * 8];
        bf8_t xf1 = *(const bf8_t*)&sA_xh[(1 * 64 + lane) * 8];
        bf8_t mf0 = *(const bf8_t*)&sA_m [(0 * 64 + lane) * 8];
        bf8_t mf1 = *(const bf8_t*)&sA_m [(1 * 64 + lane) * 8];
        f4_t accP[3][2];
        #pragma unroll
        for (int g = 0; g < 3; ++g) {
            const short* bx = wxp + (size_t)g * 16384;
            const short* bm = wmp + (size_t)g * 16384;
            #pragma unroll
            for (int nt = 0; nt < 2; ++nt) {
                const int ntG = 2 * w + nt;
                f4_t a = {0.f,0.f,0.f,0.f};
                a = MFp(xf0, BA(bx, ntG, 2, 0, lane), a);
                a = MFp(xf1, BA(bx, ntG, 2, 1, lane), a);
                a = MFp(mf0, BA(bm, ntG, 2, 0, lane), a);
                a = MFp(mf1, BA(bm, ntG, 2, 1, lane), a);
                accP[g][nt] = a;
            }
        }
        float hd2[2][4];
        #pragma unroll
        for (int nt = 0; nt < 2; ++nt) {
            const f4_t aG = nt ? accG1 : accG0;
            const int col = w * 32 + nt * 16 + c15;
            #pragma unroll
            for (int q = 0; q < 4; ++q) {
                const int r = rowb + q;
                float gh2 = __expf(-fmaxf(aG[q] + sh_bgh[col], 0.f));
                float hdv = gh2 * sh_h[r][col];
                hd2[nt][q] = hdv;
                sA_hd[((size_t)w * 64 + (((col & 31) >> 3) << 4) + r) * 8 + (col & 7)]
                    = (short)f2bf(hdv);
            }
        }
        __syncthreads();

        f4_t accZ[2] = {accP[0][0], accP[0][1]};
        f4_t accR[2] = {accP[1][0], accP[1][1]};
        #pragma unroll
        for (int kt = 0; kt < 8; ++kt) {
            bf8_t hf = *(const bf8_t*)&sA_hd[(kt * 64 + lane) * 8];
            #pragma unroll
            for (int nt = 0; nt < 2; ++nt) {
                const int ntG = 2 * w + nt;
                accZ[nt] = MFp(hf, BA(whp + 0 * 65536, ntG, 8, kt, lane), accZ[nt]);
                accR[nt] = MFp(hf, BA(whp + 1 * 65536, ntG, 8, kt, lane), accR[nt]);
            }
        }
        float zz2[2][4];
        #pragma unroll
        for (int nt = 0; nt < 2; ++nt) {
            const int col = w * 32 + nt * 16 + c15;
            #pragma unroll
            for (int q = 0; q < 4; ++q) {
                const int r = rowb + q;
                float z  = 1.f / (1.f + __expf(-(accZ[nt][q] + sh_bg[0][col])));
                float rv = 1.f / (1.f + __expf(-(accR[nt][q] + sh_bg[1][col])));
                zz2[nt][q] = z;
                sA_rhd[((size_t)w * 64 + (((col & 31) >> 3) << 4) + r) * 8 + (col & 7)]
                    = (short)f2bf(rv * hd2[nt][q]);
            }
        }
        __syncthreads();

        f4_t accH[2] = {accP[2][0], accP[2][1]};
        #pragma unroll
        for (int kt = 0; kt < 8; ++kt) {
            bf8_t hf = *(const bf8_t*)&sA_rhd[(kt * 64 + lane) * 8];
            #pragma unroll
            for (int nt = 0; nt < 2; ++nt)
                accH[nt] = MFp(hf, BA(whp + 2 * 65536, 2 * w + nt, 8, kt, lane), accH[nt]);
        }
        #pragma unroll
        for (int nt = 0; nt < 2; ++nt) {
            const int col = w * 32 + nt * 16 + c15;
            #pragma unroll
            for (int q = 0; q < 4; ++q) {
                const int r = rowb + q;
                float pre = accH[nt][q] + sh_bg[2][col];
                float a = fabsf(pre), e = __expf(-2.f * a);
                float th = copysignf((1.f - e) / (1.f + e), pre);
                sh_h[r][col] = (1.f - zz2[nt][q]) * hd2[nt][q] + zz2[nt][q] * th;
            }
        }
        __syncthreads();
    }

    if (tid < BB) {
        float s2 = 0.f;
        for (int k = 0; k < Hn; ++k) s2 = fmaf(sh_h[tid][k], W_cls[k], s2);
        out[b0 + tid] = s2 + b_cls[0];
    }
}

extern "C" void kernel_launch(void* const* d_in, const int* in_sizes, int n_in,
                              void* d_out, int out_size, void* d_ws, size_t ws_size,
                              hipStream_t stream) {
    const float* X      = (const float*)d_in[0];
    const float* M      = (const float*)d_in[1];
    const float* Dl     = (const float*)d_in[2];
    const float* x_mean = (const float*)d_in[3];
    const float* W_gx   = (const float*)d_in[4];
    const float* b_gx   = (const float*)d_in[5];
    const float* W_gh   = (const float*)d_in[6];
    const float* b_gh   = (const float*)d_in[7];
    const float* W_x    = (const float*)d_in[8];
    const float* W_h    = (const float*)d_in[9];
    const float* W_m    = (const float*)d_in[10];
    const float* b_g    = (const float*)d_in[11];
    const float* W_cls  = (const float*)d_in[12];
    const float* b_cls  = (const float*)d_in[13];
    float* out = (float*)d_out;
    short* pk  = (short*)d_ws;

    hipLaunchKernelGGL(pack_weights, dim3((PACK_SLOTS + 255) / 256), dim3(256), 0, stream,
                       W_gx, W_gh, W_x, W_h, W_m, pk);

    if (ws_size >= WS_NEED) {
        float* gxbuf = (float*)((char*)d_ws + GX_OFF);
        unsigned short* ghbuf = (unsigned short*)((char*)d_ws + GH_OFF);
        hipLaunchKernelGGL(grud_prepass, dim3(NBLK * Tn), dim3(256), 0, stream,
                           Dl, b_gx, b_gh, pk, gxbuf, ghbuf);
        hipLaunchKernelGGL(grud_rec4, dim3(NBLK), dim3(512), 0, stream,
                           X, M, x_mean, b_g, W_cls, b_cls, pk, gxbuf, ghbuf, out);
    } else {
        hipLaunchKernelGGL(grud_main, dim3(NBLK), dim3(512), 0, stream,
                           X, M, Dl, x_mean, b_gx, b_gh, b_g, W_cls, b_cls, pk, out);
    }
}

// Round 5
// 2306.339 us; speedup vs baseline: 2.6349x; 1.0049x over previous
//
#include <hip/hip_runtime.h>

// GRU-D, round 5.
// pack -> prepass1 (gamma_x f32, gamma_h bf16) -> xhat scan -> P GEMM
// -> grud_rec5 (recurrence only: hd -> z/r GEMM -> h~ GEMM -> blend).
// rec5: 32 blocks x 512 thr, waves_per_eu(2,2) pins 256-VGPR budget;
// W_h[0]/W_h[2] register-resident, W_h[1] LDS-resident; raw-barrier sync
// (lgkmcnt-only) lets gamma_h/P prefetches fly across barriers.
// Fallback to round-4 kernel if ws_size < 306 MB.

constexpr int Bn = 512, Tn = 256, Dn = 64, Hn = 256;
constexpr int BB = 16, NBLK = Bn / BB;   // 32 blocks

typedef __attribute__((ext_vector_type(8))) short bf8_t;
typedef __attribute__((ext_vector_type(4))) float f4_t;

// packed-weight region offsets in shorts
constexpr size_t OFF_WH  = 0;
constexpr size_t OFF_WX  = 196608;
constexpr size_t OFF_WM  = 245760;
constexpr size_t OFF_WGH = 294912;
constexpr size_t OFF_WGX = 311296;
constexpr int    PACK_SLOTS = 39424;

// workspace layout (bytes)
constexpr size_t GX_OFF   = (size_t)1 << 20;                     // gamma_x f32 [B][T][D]
constexpr size_t GH_OFF   = GX_OFF + (size_t)Bn * Tn * Dn * 4;   // gamma_h bf16 [B][T][H]
constexpr size_t WS_NEED  = GH_OFF + (size_t)Bn * Tn * Hn * 2;   // 101,711,872 (rec4 path)
constexpr size_t XH_OFF   = WS_NEED;                             // x_hat bf16 [B][T][D]
constexpr size_t P_OFF    = XH_OFF + (size_t)Bn * Tn * Dn * 2;   // P bf16 tile layout
constexpr size_t WS_NEED2 = P_OFF + (size_t)3 * Bn * Tn * Hn * 2; // 319,815,680

__device__ __forceinline__ unsigned short f2bf(float x) {
    union { float f; unsigned int u; } v; v.f = x;
    unsigned int r = (v.u + 0x7fffu + ((v.u >> 16) & 1u)) >> 16;   // RNE
    return (unsigned short)r;
}
__device__ __forceinline__ float bf2f(unsigned short u) {
    union { unsigned int i; float f; } v; v.i = ((unsigned int)u) << 16; return v.f;
}
__device__ __forceinline__ bf8_t LD8(const short* p) { return *(const bf8_t*)p; }
__device__ __forceinline__ f4_t MF(bf8_t a, bf8_t b, f4_t c) {
    return __builtin_amdgcn_mfma_f32_16x16x32_bf16(a, b, c, 0, 0, 0);
}
__device__ __forceinline__ f4_t MFp(bf8_t a, const short* bp, f4_t c) {
    return MF(a, LD8(bp), c);
}
__device__ __forceinline__ const short* BA(const short* p, int ntG, int KT, int kt, int lane) {
    return p + (((size_t)ntG * KT + kt) * 64 + lane) * 8;
}
// LDS-only barrier: drains ds ops, leaves global (vmcnt) prefetches in flight.
__device__ __forceinline__ void lds_sync() {
    __builtin_amdgcn_sched_barrier(0);
    asm volatile("s_waitcnt lgkmcnt(0)" ::: "memory");
    __builtin_amdgcn_s_barrier();
    __builtin_amdgcn_sched_barrier(0);
}

// ---------------------------------------------------------------------------
// pack_weights (unchanged, proven)
// ---------------------------------------------------------------------------
__global__ __launch_bounds__(256) void pack_weights(
    const float* __restrict__ W_gx, const float* __restrict__ W_gh,
    const float* __restrict__ W_x,  const float* __restrict__ W_h,
    const float* __restrict__ W_m,  short* __restrict__ out)
{
    const int slot = blockIdx.x * 256 + threadIdx.x;
    if (slot >= PACK_SLOTS) return;

    const float* w; int ldn, l, kt, j, kbase;
    if (slot < 24576) {
        int g = slot >> 13, rem = slot & 8191;
        int ntG = rem >> 9, r2 = rem & 511;
        kt = r2 >> 6; l = r2 & 63;
        j = ntG * 16 + (l & 15);
        w = W_h + (size_t)g * Hn * Hn; ldn = Hn;
    } else if (slot < 30720) {
        int s = slot - 24576;
        int g = s >> 11, rem = s & 2047;
        int ntG = rem >> 7, r2 = rem & 127;
        kt = r2 >> 6; l = r2 & 63;
        j = ntG * 16 + (l & 15);
        w = W_x + (size_t)g * Dn * Hn; ldn = Hn;
    } else if (slot < 36864) {
        int s = slot - 30720;
        int g = s >> 11, rem = s & 2047;
        int ntG = rem >> 7, r2 = rem & 127;
        kt = r2 >> 6; l = r2 & 63;
        j = ntG * 16 + (l & 15);
        w = W_m + (size_t)g * Dn * Hn; ldn = Hn;
    } else if (slot < 38912) {
        int s = slot - 36864;
        int ntG = s >> 7, r2 = s & 127;
        kt = r2 >> 6; l = r2 & 63;
        j = ntG * 16 + (l & 15);
        w = W_gh; ldn = Hn;
    } else {
        int s = slot - 38912;
        int ntG = s >> 7, r2 = s & 127;
        kt = r2 >> 6; l = r2 & 63;
        j = ntG * 16 + (l & 15);
        w = W_gx; ldn = Dn;
    }
    kbase = kt * 32 + ((l >> 4) << 3);
    bf8_t v;
    #pragma unroll
    for (int i = 0; i < 8; ++i)
        v[i] = (short)f2bf(w[(size_t)(kbase + i) * ldn + j]);
    *(bf8_t*)&out[(size_t)slot * 8] = v;
}

// ---------------------------------------------------------------------------
// prepass1 (unchanged, proven): gamma_x f32, gamma_h bf16
// ---------------------------------------------------------------------------
__global__ __launch_bounds__(256) void grud_prepass(
    const float* __restrict__ Dl, const float* __restrict__ b_gx,
    const float* __restrict__ b_gh, const short* __restrict__ pk,
    float* __restrict__ gx, unsigned short* __restrict__ gh)
{
    __shared__ short sDf[2 * 64 * 8];
    const int tid = threadIdx.x, w = tid >> 6, lane = tid & 63;
    const int bt = blockIdx.x >> 8, t = blockIdx.x & 255;
    const int b0 = bt * 16;
    const int c15 = lane & 15, rowb = (lane >> 4) * 4;

    if (w < 2) {
        const int row = lane & 15, cb = w * 32 + ((lane >> 4) << 3);
        const float* p = Dl + ((size_t)(b0 + row) * Tn + t) * Dn + cb;
        float4 a = *(const float4*)p, b = *(const float4*)(p + 4);
        bf8_t v;
        v[0]=(short)f2bf(a.x); v[1]=(short)f2bf(a.y); v[2]=(short)f2bf(a.z); v[3]=(short)f2bf(a.w);
        v[4]=(short)f2bf(b.x); v[5]=(short)f2bf(b.y); v[6]=(short)f2bf(b.z); v[7]=(short)f2bf(b.w);
        *(bf8_t*)&sDf[(w * 64 + lane) * 8] = v;
    }
    __syncthreads();
    bf8_t df0 = *(const bf8_t*)&sDf[lane * 8];
    bf8_t df1 = *(const bf8_t*)&sDf[(64 + lane) * 8];

    #pragma unroll
    for (int i = 0; i < 4; ++i) {
        const int ntG = 4 * w + i;
        f4_t acc = {0.f, 0.f, 0.f, 0.f};
        acc = MFp(df0, BA(pk + OFF_WGH, ntG, 2, 0, lane), acc);
        acc = MFp(df1, BA(pk + OFF_WGH, ntG, 2, 1, lane), acc);
        const int col = ntG * 16 + c15;
        const float bb = b_gh[col];
        #pragma unroll
        for (int q = 0; q < 4; ++q) {
            const int r = rowb + q;
            gh[((size_t)(b0 + r) * Tn + t) * Hn + col] =
                f2bf(__expf(-fmaxf(acc[q] + bb, 0.f)));
        }
    }
    {
        f4_t acc = {0.f, 0.f, 0.f, 0.f};
        acc = MFp(df0, BA(pk + OFF_WGX, w, 2, 0, lane), acc);
        acc = MFp(df1, BA(pk + OFF_WGX, w, 2, 1, lane), acc);
        const int col = w * 16 + c15;
        const float bb = b_gx[col];
        #pragma unroll
        for (int q = 0; q < 4; ++q) {
            const int r = rowb + q;
            gx[((size_t)(b0 + r) * Tn + t) * Dn + col] =
                __expf(-fmaxf(acc[q] + bb, 0.f));
        }
    }
}

// ---------------------------------------------------------------------------
// prepass2: x_hat scan. One thread per (b,d); sequential over t.
// ---------------------------------------------------------------------------
__global__ __launch_bounds__(256) void grud_xhat(
    const float* __restrict__ X, const float* __restrict__ M,
    const float* __restrict__ x_mean, const float* __restrict__ gx,
    unsigned short* __restrict__ XH)
{
    const int g = blockIdx.x * 256 + threadIdx.x;   // 32768 threads
    const int b = g >> 6, d = g & 63;
    const float xm = x_mean[d];
    float xp = 0.f;
    const size_t base = (size_t)b * Tn * Dn + d;
    for (int t = 0; t < Tn; ++t) {
        const size_t idx = base + (size_t)t * Dn;
        const float x = X[idx], m = M[idx], gv = gx[idx];
        const float xh = m * x + (1.f - m) * (gv * xp + (1.f - gv) * xm);
        xp = m * x + (1.f - m) * xp;
        XH[idx] = f2bf(xh);
    }
}

// ---------------------------------------------------------------------------
// prepass3: P[bt][g][ntG][lane][q] = (x_hat@W_x + m@W_m + b_g), bf16.
// grid = 32*256 (one block per (bblk,t) tile of 16 rows), 256 thr = 4 waves.
// ---------------------------------------------------------------------------
__global__ __launch_bounds__(256) void grud_pgemm(
    const float* __restrict__ M, const unsigned short* __restrict__ XH,
    const float* __restrict__ b_g, const short* __restrict__ pk,
    unsigned short* __restrict__ P)
{
    const int tid = threadIdx.x, w = tid >> 6, lane = tid & 63;
    const int c15 = lane & 15;
    const int bblk = blockIdx.x >> 8;
    const int b0 = bblk * 16, t = blockIdx.x & 255;

    // per-lane A-fragments (direct loads; redundant across waves, L1/L2-hot)
    const size_t abase = ((size_t)(b0 + (lane & 15)) * Tn + t) * Dn + ((lane >> 4) << 3);
    bf8_t xf[2], mf[2];
    #pragma unroll
    for (int kt = 0; kt < 2; ++kt) {
        uint4 xa = *(const uint4*)&XH[abase + kt * 32];
        union { uint4 u; bf8_t b; } cvt; cvt.u = xa;
        xf[kt] = cvt.b;
        float4 a = *(const float4*)&M[abase + kt * 32];
        float4 b = *(const float4*)&M[abase + kt * 32 + 4];
        bf8_t v;
        v[0]=(short)f2bf(a.x); v[1]=(short)f2bf(a.y); v[2]=(short)f2bf(a.z); v[3]=(short)f2bf(a.w);
        v[4]=(short)f2bf(b.x); v[5]=(short)f2bf(b.y); v[6]=(short)f2bf(b.z); v[7]=(short)f2bf(b.w);
        mf[kt] = v;
    }

    const size_t btl = (size_t)blockIdx.x;   // bblk*256 + t
    #pragma unroll
    for (int i = 0; i < 12; ++i) {
        const int p = w * 12 + i;
        const int gg = p >> 4, ntG = p & 15;
        f4_t acc = {0.f, 0.f, 0.f, 0.f};
        acc = MFp(xf[0], BA(pk + OFF_WX + (size_t)gg * 16384, ntG, 2, 0, lane), acc);
        acc = MFp(xf[1], BA(pk + OFF_WX + (size_t)gg * 16384, ntG, 2, 1, lane), acc);
        acc = MFp(mf[0], BA(pk + OFF_WM + (size_t)gg * 16384, ntG, 2, 0, lane), acc);
        acc = MFp(mf[1], BA(pk + OFF_WM + (size_t)gg * 16384, ntG, 2, 1, lane), acc);
        const float bb = b_g[gg * Hn + ntG * 16 + c15];
        ushort4 o;
        o.x = f2bf(acc[0] + bb); o.y = f2bf(acc[1] + bb);
        o.z = f2bf(acc[2] + bb); o.w = f2bf(acc[3] + bb);
        *(ushort4*)&P[(((btl * 3 + gg) * 16 + ntG) << 8) + lane * 4] = o;
    }
}

// ---------------------------------------------------------------------------
// grud_rec5: recurrence only. 32 blocks x 512 thr, exact 2 waves/EU.
// ---------------------------------------------------------------------------
__global__ __attribute__((amdgpu_flat_work_group_size(512, 512), amdgpu_waves_per_eu(2, 2)))
void grud_rec5(
    const unsigned short* __restrict__ gh, const unsigned short* __restrict__ P,
    const float* __restrict__ W_cls, const float* __restrict__ b_cls,
    const short* __restrict__ pk, float* __restrict__ out)
{
    __shared__ short sWh1[8192 * 8];             // 131072 B : W_h[1] B-frags
    __shared__ unsigned short sh_hb[16][264];    //   8448 B : h state (bf16)
    __shared__ short sA_hd [8 * 64 * 8];         //   8192 B
    __shared__ short sA_rhd[8 * 64 * 8];         //   8192 B  => 155904 B

    const int tid = threadIdx.x, w = tid >> 6, lane = tid & 63;
    const int c15 = lane & 15, rowb = (lane >> 4) * 4;
    const int b0 = blockIdx.x * BB;

    // resident weights: W_h[0] (z), W_h[2] (h~) : 128 VGPR
    bf8_t whz[2][8], whh[2][8];
    #pragma unroll
    for (int nt = 0; nt < 2; ++nt)
        #pragma unroll
        for (int kt = 0; kt < 8; ++kt) {
            whz[nt][kt] = LD8(BA(pk + OFF_WH,             2 * w + nt, 8, kt, lane));
            whh[nt][kt] = LD8(BA(pk + OFF_WH + 2 * 65536, 2 * w + nt, 8, kt, lane));
        }
    // W_h[1] -> LDS
    for (int c = tid; c < 8192; c += 512)
        *(uint4*)&sWh1[c * 8] = *(const uint4*)&pk[OFF_WH + 65536 + (size_t)c * 8];
    for (int i = tid; i < 16 * 264; i += 512) (&sh_hb[0][0])[i] = 0;

    // t = 0 prefetch
    const size_t ghA_base = ((size_t)(b0 + (lane & 15)) * Tn) * Hn + w * 32 + ((lane >> 4) << 3);
    uint4 gha = *(const uint4*)&gh[ghA_base];
    unsigned short ghcd[2][4];
    #pragma unroll
    for (int nt = 0; nt < 2; ++nt)
        #pragma unroll
        for (int q = 0; q < 4; ++q)
            ghcd[nt][q] = gh[((size_t)(b0 + rowb + q) * Tn) * Hn + w * 32 + nt * 16 + c15];
    ushort4 pz[2], pr[2], ph[2];
    {
        const size_t pb = (size_t)blockIdx.x * 256 * 3;
        #pragma unroll
        for (int nt = 0; nt < 2; ++nt) {
            pz[nt] = *(const ushort4*)&P[(((pb + 0) * 16 + 2 * w + nt) << 8) + lane * 4];
            pr[nt] = *(const ushort4*)&P[(((pb + 1) * 16 + 2 * w + nt) << 8) + lane * 4];
            ph[nt] = *(const ushort4*)&P[(((pb + 2) * 16 + 2 * w + nt) << 8) + lane * 4];
        }
    }
    __syncthreads();   // full drain once before the loop

    float h_cd[2][4] = {{0.f,0.f,0.f,0.f},{0.f,0.f,0.f,0.f}};
    float hd_cd[2][4], zzv[2][4];
    const f4_t z4 = {0.f, 0.f, 0.f, 0.f};

    for (int t = 0; t < Tn; ++t) {
        const int tn = (t + 1 < Tn) ? (t + 1) : (Tn - 1);

        // ===== PH1: hd A-frag build + t+1 prefetch issue =====
        {
            uint4 hA = *(const uint4*)&sh_hb[lane & 15][w * 32 + ((lane >> 4) << 3)];
            unsigned int ga[4] = {gha.x, gha.y, gha.z, gha.w};
            unsigned int ha[4] = {hA.x, hA.y, hA.z, hA.w};
            bf8_t hv;
            #pragma unroll
            for (int i = 0; i < 8; ++i) {
                float gf = bf2f((unsigned short)((ga[i >> 1] >> ((i & 1) * 16)) & 0xffffu));
                float hf = bf2f((unsigned short)((ha[i >> 1] >> ((i & 1) * 16)) & 0xffffu));
                hv[i] = (short)f2bf(gf * hf);
            }
            *(bf8_t*)&sA_hd[(w * 64 + lane) * 8] = hv;
        }
        #pragma unroll
        for (int nt = 0; nt < 2; ++nt)
            #pragma unroll
            for (int q = 0; q < 4; ++q)
                hd_cd[nt][q] = bf2f(ghcd[nt][q]) * h_cd[nt][q];

        // prefetch t+1 (flies across raw barriers)
        uint4 gha_n = *(const uint4*)&gh[ghA_base + (size_t)tn * Hn];
        unsigned short ghcd_n[2][4];
        #pragma unroll
        for (int nt = 0; nt < 2; ++nt)
            #pragma unroll
            for (int q = 0; q < 4; ++q)
                ghcd_n[nt][q] = gh[((size_t)(b0 + rowb + q) * Tn + tn) * Hn + w * 32 + nt * 16 + c15];
        ushort4 pz_n[2], pr_n[2], ph_n[2];
        {
            const size_t pb = ((size_t)blockIdx.x * 256 + tn) * 3;
            #pragma unroll
            for (int nt = 0; nt < 2; ++nt) {
                pz_n[nt] = *(const ushort4*)&P[(((pb + 0) * 16 + 2 * w + nt) << 8) + lane * 4];
                pr_n[nt] = *(const ushort4*)&P[(((pb + 1) * 16 + 2 * w + nt) << 8) + lane * 4];
                ph_n[nt] = *(const ushort4*)&P[(((pb + 2) * 16 + 2 * w + nt) << 8) + lane * 4];
            }
        }
        lds_sync();   // bar0

        // ===== PH2: z and r GEMMs =====
        f4_t aZ[2] = {z4, z4}, aR[2] = {z4, z4};
        #pragma unroll
        for (int kt = 0; kt < 8; ++kt) {
            bf8_t hf  = LD8(&sA_hd[(kt * 64 + lane) * 8]);
            bf8_t wr0 = LD8(&sWh1[((2 * w + 0) * 8 + kt) * 512 + lane * 8]);
            bf8_t wr1 = LD8(&sWh1[((2 * w + 1) * 8 + kt) * 512 + lane * 8]);
            aZ[0] = MF(hf, whz[0][kt], aZ[0]);
            aZ[1] = MF(hf, whz[1][kt], aZ[1]);
            aR[0] = MF(hf, wr0, aR[0]);
            aR[1] = MF(hf, wr1, aR[1]);
        }
        #pragma unroll
        for (int nt = 0; nt < 2; ++nt) {
            const int col = w * 32 + nt * 16 + c15;
            #pragma unroll
            for (int q = 0; q < 4; ++q) {
                const int r = rowb + q;
                float z  = 1.f / (1.f + __expf(-(aZ[nt][q] + bf2f(((const unsigned short*)&pz[nt])[q]))));
                float rr = 1.f / (1.f + __expf(-(aR[nt][q] + bf2f(((const unsigned short*)&pr[nt])[q]))));
                zzv[nt][q] = z;
                sA_rhd[(w * 64 + ((col & 31) >> 3) * 16 + r) * 8 + (col & 7)] =
                    (short)f2bf(rr * hd_cd[nt][q]);
            }
        }
        lds_sync();   // bar1

        // ===== PH3: h~ GEMM + h update =====
        f4_t aH[2] = {z4, z4};
        #pragma unroll
        for (int kt = 0; kt < 8; ++kt) {
            bf8_t rf = LD8(&sA_rhd[(kt * 64 + lane) * 8]);
            aH[0] = MF(rf, whh[0][kt], aH[0]);
            aH[1] = MF(rf, whh[1][kt], aH[1]);
        }
        #pragma unroll
        for (int nt = 0; nt < 2; ++nt) {
            const int col = w * 32 + nt * 16 + c15;
            #pragma unroll
            for (int q = 0; q < 4; ++q) {
                const int r = rowb + q;
                float pre = aH[nt][q] + bf2f(((const unsigned short*)&ph[nt])[q]);
                float a = fabsf(pre), e = __expf(-2.f * a);
                float th = copysignf((1.f - e) / (1.f + e), pre);
                float hn = (1.f - zzv[nt][q]) * hd_cd[nt][q] + zzv[nt][q] * th;
                h_cd[nt][q] = hn;
                sh_hb[r][col] = f2bf(hn);
            }
        }
        lds_sync();   // bar2

        // rotate prefetch registers
        gha = gha_n;
        #pragma unroll
        for (int nt = 0; nt < 2; ++nt) {
            #pragma unroll
            for (int q = 0; q < 4; ++q) ghcd[nt][q] = ghcd_n[nt][q];
            pz[nt] = pz_n[nt]; pr[nt] = pr_n[nt]; ph[nt] = ph_n[nt];
        }
    }

    // ---- classifier ----
    #pragma unroll
    for (int rr2 = 0; rr2 < 2; ++rr2) {
        const int row = w * 2 + rr2;
        ushort4 hb = *(const ushort4*)&sh_hb[row][lane * 4];
        float4 wv  = *(const float4*)&W_cls[lane * 4];
        float p = bf2f(hb.x) * wv.x + bf2f(hb.y) * wv.y +
                  bf2f(hb.z) * wv.z + bf2f(hb.w) * wv.w;
        #pragma unroll
        for (int o = 32; o > 0; o >>= 1) p += __shfl_down(p, o, 64);
        if (lane == 0) out[b0 + row] = p + b_cls[0];
    }
}

// ---------------------------------------------------------------------------
// Fallback: round-4 kernel (proven 2318 us) if ws_size < WS_NEED2
// ---------------------------------------------------------------------------
__global__ __launch_bounds__(512, 2) void grud_rec4(
    const float* __restrict__ X, const float* __restrict__ M,
    const float* __restrict__ x_mean, const float* __restrict__ b_g,
    const float* __restrict__ W_cls, const float* __restrict__ b_cls,
    const short* __restrict__ pk, const float* __restrict__ gx,
    const unsigned short* __restrict__ gh, float* __restrict__ out)
{
    __shared__ short sWh1[16 * 8 * 64 * 8];
    __shared__ unsigned short sh_hb[16][264];
    __shared__ short sA_xh[2 * 64 * 8];
    __shared__ short sA_m [2 * 64 * 8];
    __shared__ short sA_hd[8 * 64 * 8];
    __shared__ short sA_rhd[8 * 64 * 8];

    const int tid = threadIdx.x, w = tid >> 6, lane = tid & 63;
    const int c15 = lane & 15, rowb = (lane >> 4) * 4;
    const int b0 = blockIdx.x * BB;

    bf8_t whz[2][8], whh[2][8];
    #pragma unroll
    for (int nt = 0; nt < 2; ++nt)
        #pragma unroll
        for (int kt = 0; kt < 8; ++kt) {
            whz[nt][kt] = LD8(BA(pk + OFF_WH,             2 * w + nt, 8, kt, lane));
            whh[nt][kt] = LD8(BA(pk + OFF_WH + 2 * 65536, 2 * w + nt, 8, kt, lane));
        }
    for (int c = tid; c < 8192; c += 512)
        *(uint4*)&sWh1[c * 8] = *(const uint4*)&pk[OFF_WH + 65536 + (size_t)c * 8];
    for (int i = tid; i < 16 * 264; i += 512) (&sh_hb[0][0])[i] = 0;

    const float bz[2] = { b_g[0 * Hn + w * 32 + c15], b_g[0 * Hn + w * 32 + 16 + c15] };
    const float brr[2]= { b_g[1 * Hn + w * 32 + c15], b_g[1 * Hn + w * 32 + 16 + c15] };
    const float bh[2] = { b_g[2 * Hn + w * 32 + c15], b_g[2 * Hn + w * 32 + 16 + c15] };

    const int s    = w * 32 + (lane & 31);
    const int kt2  = s >> 7, fl = (s >> 1) & 63, half = s & 1;
    const int brow = fl & 15, bcol = kt2 * 32 + ((fl >> 4) << 3) + half * 4;
    const size_t brow_base = ((size_t)(b0 + brow) * Tn) * Dn + bcol;

    float xb[4] = {0.f, 0.f, 0.f, 0.f};
    float xp[4] = {0.f, 0.f, 0.f, 0.f};
    float4 mv, xv = {0,0,0,0}, gxv = {0,0,0,0};
    if (lane < 32) {
        xb[0]=x_mean[bcol]; xb[1]=x_mean[bcol+1]; xb[2]=x_mean[bcol+2]; xb[3]=x_mean[bcol+3];
        xv  = *(const float4*)&X[brow_base];
        gxv = *(const float4*)&gx[brow_base];
    }
    mv = *(const float4*)&M[brow_base];

    const size_t ghA_base  = ((size_t)(b0 + (lane & 15)) * Tn) * Hn + w * 32 + ((lane >> 4) << 3);
    uint4 gha = *(const uint4*)&gh[ghA_base];
    unsigned short ghcd[2][4];
    #pragma unroll
    for (int nt = 0; nt < 2; ++nt)
        #pragma unroll
        for (int q = 0; q < 4; ++q)
            ghcd[nt][q] = gh[((size_t)(b0 + rowb + q) * Tn) * Hn + w * 32 + nt * 16 + c15];

    float h_cd[2][4] = {{0.f,0.f,0.f,0.f},{0.f,0.f,0.f,0.f}};
    float hd_cd[2][4], zz[2][4];
    const f4_t z4 = {0.f, 0.f, 0.f, 0.f};
    __syncthreads();

    for (int t = 0; t < Tn; ++t) {
        const int tn = (t + 1 < Tn) ? (t + 1) : (Tn - 1);
        {
            uint4 hA = *(const uint4*)&sh_hb[lane & 15][w * 32 + ((lane >> 4) << 3)];
            unsigned int ga[4] = {gha.x, gha.y, gha.z, gha.w};
            unsigned int ha[4] = {hA.x, hA.y, hA.z, hA.w};
            bf8_t hv;
            #pragma unroll
            for (int i = 0; i < 8; ++i) {
                float gf = bf2f((unsigned short)((ga[i >> 1] >> ((i & 1) * 16)) & 0xffffu));
                float hf = bf2f((unsigned short)((ha[i >> 1] >> ((i & 1) * 16)) & 0xffffu));
                hv[i] = (short)f2bf(gf * hf);
            }
            *(bf8_t*)&sA_hd[(w * 64 + lane) * 8] = hv;
        }
        #pragma unroll
        for (int nt = 0; nt < 2; ++nt)
            #pragma unroll
            for (int q = 0; q < 4; ++q)
                hd_cd[nt][q] = bf2f(ghcd[nt][q]) * h_cd[nt][q];

        if (lane < 32) {
            float mm[4] = {mv.x, mv.y, mv.z, mv.w};
            float xx[4] = {xv.x, xv.y, xv.z, xv.w};
            float gg[4] = {gxv.x, gxv.y, gxv.z, gxv.w};
            float xh[4];
            #pragma unroll
            for (int j = 0; j < 4; ++j) {
                xh[j] = mm[j] * xx[j] + (1.f - mm[j]) * (gg[j] * xp[j] + (1.f - gg[j]) * xb[j]);
                xp[j] = mm[j] * xx[j] + (1.f - mm[j]) * xp[j];
            }
            uint2 dd;
            dd.x = (unsigned int)f2bf(xh[0]) | ((unsigned int)f2bf(xh[1]) << 16);
            dd.y = (unsigned int)f2bf(xh[2]) | ((unsigned int)f2bf(xh[3]) << 16);
            *(uint2*)&sA_xh[(kt2 * 64 + fl) * 8 + half * 4] = dd;
        } else {
            uint2 dd;
            dd.x = (unsigned int)f2bf(mv.x) | ((unsigned int)f2bf(mv.y) << 16);
            dd.y = (unsigned int)f2bf(mv.z) | ((unsigned int)f2bf(mv.w) << 16);
            *(uint2*)&sA_m[(kt2 * 64 + fl) * 8 + half * 4] = dd;
        }
        {
            const size_t ba = brow_base + (size_t)tn * Dn;
            mv = *(const float4*)&M[ba];
            if (lane < 32) {
                xv  = *(const float4*)&X[ba];
                gxv = *(const float4*)&gx[ba];
            }
            gha = *(const uint4*)&gh[ghA_base + (size_t)tn * Hn];
            #pragma unroll
            for (int nt = 0; nt < 2; ++nt)
                #pragma unroll
                for (int q = 0; q < 4; ++q)
                    ghcd[nt][q] = gh[((size_t)(b0 + rowb + q) * Tn + tn) * Hn + w * 32 + nt * 16 + c15];
        }
        __syncthreads();

        bf8_t wxz[2][2], wxr[2][2], wmz[2][2], wmr[2][2];
        #pragma unroll
        for (int nt = 0; nt < 2; ++nt)
            #pragma unroll
            for (int kt = 0; kt < 2; ++kt) {
                wxz[nt][kt] = LD8(BA(pk + OFF_WX,         2 * w + nt, 2, kt, lane));
                wxr[nt][kt] = LD8(BA(pk + OFF_WX + 16384, 2 * w + nt, 2, kt, lane));
                wmz[nt][kt] = LD8(BA(pk + OFF_WM,         2 * w + nt, 2, kt, lane));
                wmr[nt][kt] = LD8(BA(pk + OFF_WM + 16384, 2 * w + nt, 2, kt, lane));
            }
        bf8_t xf0 = LD8(&sA_xh[lane * 8]), xf1 = LD8(&sA_xh[(64 + lane) * 8]);
        bf8_t mf0 = LD8(&sA_m [lane * 8]), mf1 = LD8(&sA_m [(64 + lane) * 8]);

        f4_t aZ[2] = {z4, z4}, aR[2] = {z4, z4};
        #pragma unroll
        for (int kt = 0; kt < 8; ++kt) {
            bf8_t hf  = LD8(&sA_hd[(kt * 64 + lane) * 8]);
            bf8_t wr0 = LD8(&sWh1[((2 * w + 0) * 8 + kt) * 512 + lane * 8]);
            bf8_t wr1 = LD8(&sWh1[((2 * w + 1) * 8 + kt) * 512 + lane * 8]);
            aZ[0] = MF(hf, whz[0][kt], aZ[0]);
            aZ[1] = MF(hf, whz[1][kt], aZ[1]);
            aR[0] = MF(hf, wr0, aR[0]);
            aR[1] = MF(hf, wr1, aR[1]);
        }
        #pragma unroll
        for (int nt = 0; nt < 2; ++nt) {
            aZ[nt] = MF(xf0, wxz[nt][0], aZ[nt]); aZ[nt] = MF(xf1, wxz[nt][1], aZ[nt]);
            aZ[nt] = MF(mf0, wmz[nt][0], aZ[nt]); aZ[nt] = MF(mf1, wmz[nt][1], aZ[nt]);
            aR[nt] = MF(xf0, wxr[nt][0], aR[nt]); aR[nt] = MF(xf1, wxr[nt][1], aR[nt]);
            aR[nt] = MF(mf0, wmr[nt][0], aR[nt]); aR[nt] = MF(mf1, wmr[nt][1], aR[nt]);
        }
        bf8_t wxh[2][2], wmh[2][2];
        #pragma unroll
        for (int nt = 0; nt < 2; ++nt)
            #pragma unroll
            for (int kt = 0; kt < 2; ++kt) {
                wxh[nt][kt] = LD8(BA(pk + OFF_WX + 32768, 2 * w + nt, 2, kt, lane));
                wmh[nt][kt] = LD8(BA(pk + OFF_WM + 32768, 2 * w + nt, 2, kt, lane));
            }
        #pragma unroll
        for (int nt = 0; nt < 2; ++nt) {
            const int col = w * 32 + nt * 16 + c15;
            #pragma unroll
            for (int q = 0; q < 4; ++q) {
                const int r = rowb + q;
                float z  = 1.f / (1.f + __expf(-(aZ[nt][q] + bz[nt])));
                float rr = 1.f / (1.f + __expf(-(aR[nt][q] + brr[nt])));
                zz[nt][q] = z;
                sA_rhd[(w * 64 + ((col & 31) >> 3) * 16 + r) * 8 + (col & 7)] =
                    (short)f2bf(rr * hd_cd[nt][q]);
            }
        }
        __syncthreads();

        f4_t aH[2] = {z4, z4};
        #pragma unroll
        for (int kt = 0; kt < 8; ++kt) {
            bf8_t rf = LD8(&sA_rhd[(kt * 64 + lane) * 8]);
            aH[0] = MF(rf, whh[0][kt], aH[0]);
            aH[1] = MF(rf, whh[1][kt], aH[1]);
        }
        #pragma unroll
        for (int nt = 0; nt < 2; ++nt) {
            aH[nt] = MF(xf0, wxh[nt][0], aH[nt]); aH[nt] = MF(xf1, wxh[nt][1], aH[nt]);
            aH[nt] = MF(mf0, wmh[nt][0], aH[nt]); aH[nt] = MF(mf1, wmh[nt][1], aH[nt]);
        }
        #pragma unroll
        for (int nt = 0; nt < 2; ++nt) {
            const int col = w * 32 + nt * 16 + c15;
            #pragma unroll
            for (int q = 0; q < 4; ++q) {
                const int r = rowb + q;
                float pre = aH[nt][q] + bh[nt];
                float a = fabsf(pre), e = __expf(-2.f * a);
                float th = copysignf((1.f - e) / (1.f + e), pre);
                float hn = (1.f - zz[nt][q]) * hd_cd[nt][q] + zz[nt][q] * th;
                h_cd[nt][q] = hn;
                sh_hb[r][col] = f2bf(hn);
            }
        }
        __syncthreads();
    }

    #pragma unroll
    for (int rr2 = 0; rr2 < 2; ++rr2) {
        const int row = w * 2 + rr2;
        ushort4 hb = *(const ushort4*)&sh_hb[row][lane * 4];
        float4 wv  = *(const float4*)&W_cls[lane * 4];
        float p = bf2f(hb.x) * wv.x + bf2f(hb.y) * wv.y +
                  bf2f(hb.z) * wv.z + bf2f(hb.w) * wv.w;
        #pragma unroll
        for (int o = 32; o > 0; o >>= 1) p += __shfl_down(p, o, 64);
        if (lane == 0) out[b0 + row] = p + b_cls[0];
    }
}

extern "C" void kernel_launch(void* const* d_in, const int* in_sizes, int n_in,
                              void* d_out, int out_size, void* d_ws, size_t ws_size,
                              hipStream_t stream) {
    const float* X      = (const float*)d_in[0];
    const float* M      = (const float*)d_in[1];
    const float* Dl     = (const float*)d_in[2];
    const float* x_mean = (const float*)d_in[3];
    const float* W_gx   = (const float*)d_in[4];
    const float* b_gx   = (const float*)d_in[5];
    const float* W_gh   = (const float*)d_in[6];
    const float* b_gh   = (const float*)d_in[7];
    const float* W_x    = (const float*)d_in[8];
    const float* W_h    = (const float*)d_in[9];
    const float* W_m    = (const float*)d_in[10];
    const float* b_g    = (const float*)d_in[11];
    const float* W_cls  = (const float*)d_in[12];
    const float* b_cls  = (const float*)d_in[13];
    float* out = (float*)d_out;
    short* pk  = (short*)d_ws;

    hipLaunchKernelGGL(pack_weights, dim3((PACK_SLOTS + 255) / 256), dim3(256), 0, stream,
                       W_gx, W_gh, W_x, W_h, W_m, pk);

    float*          gxbuf = (float*)((char*)d_ws + GX_OFF);
    unsigned short* ghbuf = (unsigned short*)((char*)d_ws + GH_OFF);

    hipLaunchKernelGGL(grud_prepass, dim3(NBLK * Tn), dim3(256), 0, stream,
                       Dl, b_gx, b_gh, pk, gxbuf, ghbuf);

    if (ws_size >= WS_NEED2) {
        unsigned short* xhbuf = (unsigned short*)((char*)d_ws + XH_OFF);
        unsigned short* pbuf  = (unsigned short*)((char*)d_ws + P_OFF);
        hipLaunchKernelGGL(grud_xhat, dim3(Bn * Dn / 256), dim3(256), 0, stream,
                           X, M, x_mean, gxbuf, xhbuf);
        hipLaunchKernelGGL(grud_pgemm, dim3(NBLK * Tn), dim3(256), 0, stream,
                           M, xhbuf, b_g, pk, pbuf);
        hipLaunchKernelGGL(grud_rec5, dim3(NBLK), dim3(512), 0, stream,
                           ghbuf, pbuf, W_cls, b_cls, pk, out);
    } else {
        hipLaunchKernelGGL(grud_rec4, dim3(NBLK), dim3(512), 0, stream,
                           X, M, x_mean, b_g, W_cls, b_cls, pk, gxbuf, ghbuf, out);
    }
}

// Round 8
// 2242.976 us; speedup vs baseline: 2.7094x; 1.0282x over previous
//
#include <hip/hip_runtime.h>

// GRU-D, round 8.
// pack -> prepass (gamma_x f32, gamma_h bf16) -> grud_rec8.
// rec8 = rec4 (proven 2318us, 128 VGPR, compiles clean) with ONE change:
// the three in-loop __syncthreads() are replaced by lgkmcnt-only barriers
// (lds_sync), so the ~12 HBM/L2 prefetch loads issued in PH1 stay in
// flight across all barriers instead of being drained by vmcnt(0) 3x/step.
// Register-resident weights abandoned (R4/R6/R7: remat / LDS-promotion).

constexpr int Bn = 512, Tn = 256, Dn = 64, Hn = 256;
constexpr int BB = 16, NBLK = Bn / BB;   // 32 blocks

typedef __attribute__((ext_vector_type(8))) short bf8_t;
typedef __attribute__((ext_vector_type(4))) float f4_t;

constexpr size_t OFF_WH  = 0;
constexpr size_t OFF_WX  = 196608;
constexpr size_t OFF_WM  = 245760;
constexpr size_t OFF_WGH = 294912;
constexpr size_t OFF_WGX = 311296;
constexpr int    PACK_SLOTS = 39424;

constexpr size_t GX_OFF  = (size_t)1 << 20;
constexpr size_t GH_OFF  = GX_OFF + (size_t)Bn * Tn * Dn * 4;
constexpr size_t WS_NEED = GH_OFF + (size_t)Bn * Tn * Hn * 2;    // 101,711,872

__device__ __forceinline__ unsigned short f2bf(float x) {
    union { float f; unsigned int u; } v; v.f = x;
    unsigned int r = (v.u + 0x7fffu + ((v.u >> 16) & 1u)) >> 16;   // RNE
    return (unsigned short)r;
}
__device__ __forceinline__ float bf2f(unsigned short u) {
    union { unsigned int i; float f; } v; v.i = ((unsigned int)u) << 16; return v.f;
}
__device__ __forceinline__ bf8_t LD8(const short* p) { return *(const bf8_t*)p; }
__device__ __forceinline__ f4_t MF(bf8_t a, bf8_t b, f4_t c) {
    return __builtin_amdgcn_mfma_f32_16x16x32_bf16(a, b, c, 0, 0, 0);
}
__device__ __forceinline__ f4_t MFp(bf8_t a, const short* bp, f4_t c) {
    return MF(a, LD8(bp), c);
}
__device__ __forceinline__ const short* BA(const short* p, int ntG, int KT, int kt, int lane) {
    return p + (((size_t)ntG * KT + kt) * 64 + lane) * 8;
}
// LDS-only barrier: drains LDS ops, leaves global (vmcnt) loads in flight.
__device__ __forceinline__ void lds_sync() {
    __builtin_amdgcn_sched_barrier(0);
    asm volatile("s_waitcnt lgkmcnt(0)" ::: "memory");
    __builtin_amdgcn_s_barrier();
    __builtin_amdgcn_sched_barrier(0);
}

// ---------------------------------------------------------------------------
// pack_weights (unchanged, proven)
// ---------------------------------------------------------------------------
__global__ __launch_bounds__(256) void pack_weights(
    const float* __restrict__ W_gx, const float* __restrict__ W_gh,
    const float* __restrict__ W_x,  const float* __restrict__ W_h,
    const float* __restrict__ W_m,  short* __restrict__ out)
{
    const int slot = blockIdx.x * 256 + threadIdx.x;
    if (slot >= PACK_SLOTS) return;

    const float* w; int ldn, l, kt, j, kbase;
    if (slot < 24576) {
        int g = slot >> 13, rem = slot & 8191;
        int ntG = rem >> 9, r2 = rem & 511;
        kt = r2 >> 6; l = r2 & 63;
        j = ntG * 16 + (l & 15);
        w = W_h + (size_t)g * Hn * Hn; ldn = Hn;
    } else if (slot < 30720) {
        int s = slot - 24576;
        int g = s >> 11, rem = s & 2047;
        int ntG = rem >> 7, r2 = rem & 127;
        kt = r2 >> 6; l = r2 & 63;
        j = ntG * 16 + (l & 15);
        w = W_x + (size_t)g * Dn * Hn; ldn = Hn;
    } else if (slot < 36864) {
        int s = slot - 30720;
        int g = s >> 11, rem = s & 2047;
        int ntG = rem >> 7, r2 = rem & 127;
        kt = r2 >> 6; l = r2 & 63;
        j = ntG * 16 + (l & 15);
        w = W_m + (size_t)g * Dn * Hn; ldn = Hn;
    } else if (slot < 38912) {
        int s = slot - 36864;
        int ntG = s >> 7, r2 = s & 127;
        kt = r2 >> 6; l = r2 & 63;
        j = ntG * 16 + (l & 15);
        w = W_gh; ldn = Hn;
    } else {
        int s = slot - 38912;
        int ntG = s >> 7, r2 = s & 127;
        kt = r2 >> 6; l = r2 & 63;
        j = ntG * 16 + (l & 15);
        w = W_gx; ldn = Dn;
    }
    kbase = kt * 32 + ((l >> 4) << 3);
    bf8_t v;
    #pragma unroll
    for (int i = 0; i < 8; ++i)
        v[i] = (short)f2bf(w[(size_t)(kbase + i) * ldn + j]);
    *(bf8_t*)&out[(size_t)slot * 8] = v;
}

// ---------------------------------------------------------------------------
// prepass (unchanged, proven)
// ---------------------------------------------------------------------------
__global__ __launch_bounds__(256) void grud_prepass(
    const float* __restrict__ Dl, const float* __restrict__ b_gx,
    const float* __restrict__ b_gh, const short* __restrict__ pk,
    float* __restrict__ gx, unsigned short* __restrict__ gh)
{
    __shared__ short sDf[2 * 64 * 8];
    const int tid = threadIdx.x, w = tid >> 6, lane = tid & 63;
    const int bt = blockIdx.x >> 8, t = blockIdx.x & 255;
    const int b0 = bt * 16;
    const int c15 = lane & 15, rowb = (lane >> 4) * 4;

    if (w < 2) {
        const int row = lane & 15, cb = w * 32 + ((lane >> 4) << 3);
        const float* p = Dl + ((size_t)(b0 + row) * Tn + t) * Dn + cb;
        float4 a = *(const float4*)p, b = *(const float4*)(p + 4);
        bf8_t v;
        v[0]=(short)f2bf(a.x); v[1]=(short)f2bf(a.y); v[2]=(short)f2bf(a.z); v[3]=(short)f2bf(a.w);
        v[4]=(short)f2bf(b.x); v[5]=(short)f2bf(b.y); v[6]=(short)f2bf(b.z); v[7]=(short)f2bf(b.w);
        *(bf8_t*)&sDf[(w * 64 + lane) * 8] = v;
    }
    __syncthreads();
    bf8_t df0 = *(const bf8_t*)&sDf[lane * 8];
    bf8_t df1 = *(const bf8_t*)&sDf[(64 + lane) * 8];

    #pragma unroll
    for (int i = 0; i < 4; ++i) {
        const int ntG = 4 * w + i;
        f4_t acc = {0.f, 0.f, 0.f, 0.f};
        acc = MFp(df0, BA(pk + OFF_WGH, ntG, 2, 0, lane), acc);
        acc = MFp(df1, BA(pk + OFF_WGH, ntG, 2, 1, lane), acc);
        const int col = ntG * 16 + c15;
        const float bb = b_gh[col];
        #pragma unroll
        for (int q = 0; q < 4; ++q) {
            const int r = rowb + q;
            gh[((size_t)(b0 + r) * Tn + t) * Hn + col] =
                f2bf(__expf(-fmaxf(acc[q] + bb, 0.f)));
        }
    }
    {
        f4_t acc = {0.f, 0.f, 0.f, 0.f};
        acc = MFp(df0, BA(pk + OFF_WGX, w, 2, 0, lane), acc);
        acc = MFp(df1, BA(pk + OFF_WGX, w, 2, 1, lane), acc);
        const int col = w * 16 + c15;
        const float bb = b_gx[col];
        #pragma unroll
        for (int q = 0; q < 4; ++q) {
            const int r = rowb + q;
            gx[((size_t)(b0 + r) * Tn + t) * Dn + col] =
                __expf(-fmaxf(acc[q] + bb, 0.f));
        }
    }
}

// ---------------------------------------------------------------------------
// grud_rec8: rec4 with lgkmcnt-only in-loop barriers.
// ---------------------------------------------------------------------------
__global__ __launch_bounds__(512, 2) void grud_rec8(
    const float* __restrict__ X, const float* __restrict__ M,
    const float* __restrict__ x_mean, const float* __restrict__ b_g,
    const float* __restrict__ W_cls, const float* __restrict__ b_cls,
    const short* __restrict__ pk, const float* __restrict__ gx,
    const unsigned short* __restrict__ gh, float* __restrict__ out)
{
    __shared__ short sWh1[16 * 8 * 64 * 8];      // 131072 B : W_h[1] B-frags
    __shared__ unsigned short sh_hb[16][264];    //   8448 B : h state (bf16)
    __shared__ short sA_xh[2 * 64 * 8];
    __shared__ short sA_m [2 * 64 * 8];
    __shared__ short sA_hd[8 * 64 * 8];
    __shared__ short sA_rhd[8 * 64 * 8];         // => 160256 B total

    const int tid = threadIdx.x, w = tid >> 6, lane = tid & 63;
    const int c15 = lane & 15, rowb = (lane >> 4) * 4;
    const int b0 = blockIdx.x * BB;

    // W_h[0]/W_h[2] "resident" declarations (compiler remats; harmless)
    bf8_t whz[2][8], whh[2][8];
    #pragma unroll
    for (int nt = 0; nt < 2; ++nt)
        #pragma unroll
        for (int kt = 0; kt < 8; ++kt) {
            whz[nt][kt] = LD8(BA(pk + OFF_WH,             2 * w + nt, 8, kt, lane));
            whh[nt][kt] = LD8(BA(pk + OFF_WH + 2 * 65536, 2 * w + nt, 8, kt, lane));
        }
    for (int c = tid; c < 8192; c += 512)
        *(uint4*)&sWh1[c * 8] = *(const uint4*)&pk[OFF_WH + 65536 + (size_t)c * 8];
    for (int i = tid; i < 16 * 264; i += 512) (&sh_hb[0][0])[i] = 0;

    const float bz[2] = { b_g[0 * Hn + w * 32 + c15], b_g[0 * Hn + w * 32 + 16 + c15] };
    const float brr[2]= { b_g[1 * Hn + w * 32 + c15], b_g[1 * Hn + w * 32 + 16 + c15] };
    const float bh[2] = { b_g[2 * Hn + w * 32 + c15], b_g[2 * Hn + w * 32 + 16 + c15] };

    const int s    = w * 32 + (lane & 31);
    const int kt2  = s >> 7, fl = (s >> 1) & 63, half = s & 1;
    const int brow = fl & 15, bcol = kt2 * 32 + ((fl >> 4) << 3) + half * 4;
    const size_t brow_base = ((size_t)(b0 + brow) * Tn) * Dn + bcol;

    float xb[4] = {0.f, 0.f, 0.f, 0.f};
    float xp[4] = {0.f, 0.f, 0.f, 0.f};
    float4 mv, xv = {0,0,0,0}, gxv = {0,0,0,0};
    if (lane < 32) {
        xb[0]=x_mean[bcol]; xb[1]=x_mean[bcol+1]; xb[2]=x_mean[bcol+2]; xb[3]=x_mean[bcol+3];
        xv  = *(const float4*)&X[brow_base];
        gxv = *(const float4*)&gx[brow_base];
    }
    mv = *(const float4*)&M[brow_base];

    const size_t ghA_base  = ((size_t)(b0 + (lane & 15)) * Tn) * Hn + w * 32 + ((lane >> 4) << 3);
    uint4 gha = *(const uint4*)&gh[ghA_base];
    unsigned short ghcd[2][4];
    #pragma unroll
    for (int nt = 0; nt < 2; ++nt)
        #pragma unroll
        for (int q = 0; q < 4; ++q)
            ghcd[nt][q] = gh[((size_t)(b0 + rowb + q) * Tn) * Hn + w * 32 + nt * 16 + c15];

    float h_cd[2][4] = {{0.f,0.f,0.f,0.f},{0.f,0.f,0.f,0.f}};
    float hd_cd[2][4], zz[2][4];
    const f4_t z4 = {0.f, 0.f, 0.f, 0.f};
    __syncthreads();   // one full barrier before the loop

    for (int t = 0; t < Tn; ++t) {
        const int tn = (t + 1 < Tn) ? (t + 1) : (Tn - 1);

        // ===== PH1: A-frag builds + t+1 prefetch =====
        {
            uint4 hA = *(const uint4*)&sh_hb[lane & 15][w * 32 + ((lane >> 4) << 3)];
            unsigned int ga[4] = {gha.x, gha.y, gha.z, gha.w};
            unsigned int ha[4] = {hA.x, hA.y, hA.z, hA.w};
            bf8_t hv;
            #pragma unroll
            for (int i = 0; i < 8; ++i) {
                float gf = bf2f((unsigned short)((ga[i >> 1] >> ((i & 1) * 16)) & 0xffffu));
                float hf = bf2f((unsigned short)((ha[i >> 1] >> ((i & 1) * 16)) & 0xffffu));
                hv[i] = (short)f2bf(gf * hf);
            }
            *(bf8_t*)&sA_hd[(w * 64 + lane) * 8] = hv;
        }
        #pragma unroll
        for (int nt = 0; nt < 2; ++nt)
            #pragma unroll
            for (int q = 0; q < 4; ++q)
                hd_cd[nt][q] = bf2f(ghcd[nt][q]) * h_cd[nt][q];

        if (lane < 32) {
            float mm[4] = {mv.x, mv.y, mv.z, mv.w};
            float xx[4] = {xv.x, xv.y, xv.z, xv.w};
            float gg[4] = {gxv.x, gxv.y, gxv.z, gxv.w};
            float xh[4];
            #pragma unroll
            for (int j = 0; j < 4; ++j) {
                xh[j] = mm[j] * xx[j] + (1.f - mm[j]) * (gg[j] * xp[j] + (1.f - gg[j]) * xb[j]);
                xp[j] = mm[j] * xx[j] + (1.f - mm[j]) * xp[j];
            }
            uint2 dd;
            dd.x = (unsigned int)f2bf(xh[0]) | ((unsigned int)f2bf(xh[1]) << 16);
            dd.y = (unsigned int)f2bf(xh[2]) | ((unsigned int)f2bf(xh[3]) << 16);
            *(uint2*)&sA_xh[(kt2 * 64 + fl) * 8 + half * 4] = dd;
        } else {
            uint2 dd;
            dd.x = (unsigned int)f2bf(mv.x) | ((unsigned int)f2bf(mv.y) << 16);
            dd.y = (unsigned int)f2bf(mv.z) | ((unsigned int)f2bf(mv.w) << 16);
            *(uint2*)&sA_m[(kt2 * 64 + fl) * 8 + half * 4] = dd;
        }
        {   // t+1 prefetch — rides across the lgkmcnt-only barriers
            const size_t ba = brow_base + (size_t)tn * Dn;
            mv = *(const float4*)&M[ba];
            if (lane < 32) {
                xv  = *(const float4*)&X[ba];
                gxv = *(const float4*)&gx[ba];
            }
            gha = *(const uint4*)&gh[ghA_base + (size_t)tn * Hn];
            #pragma unroll
            for (int nt = 0; nt < 2; ++nt)
                #pragma unroll
                for (int q = 0; q < 4; ++q)
                    ghcd[nt][q] = gh[((size_t)(b0 + rowb + q) * Tn + tn) * Hn + w * 32 + nt * 16 + c15];
        }
        lds_sync();   // bar0 — no vmcnt drain

        // ===== PH2: z and r gates =====
        bf8_t wxz[2][2], wxr[2][2], wmz[2][2], wmr[2][2];
        #pragma unroll
        for (int nt = 0; nt < 2; ++nt)
            #pragma unroll
            for (int kt = 0; kt < 2; ++kt) {
                wxz[nt][kt] = LD8(BA(pk + OFF_WX,         2 * w + nt, 2, kt, lane));
                wxr[nt][kt] = LD8(BA(pk + OFF_WX + 16384, 2 * w + nt, 2, kt, lane));
                wmz[nt][kt] = LD8(BA(pk + OFF_WM,         2 * w + nt, 2, kt, lane));
                wmr[nt][kt] = LD8(BA(pk + OFF_WM + 16384, 2 * w + nt, 2, kt, lane));
            }
        bf8_t xf0 = LD8(&sA_xh[lane * 8]), xf1 = LD8(&sA_xh[(64 + lane) * 8]);
        bf8_t mf0 = LD8(&sA_m [lane * 8]), mf1 = LD8(&sA_m [(64 + lane) * 8]);

        f4_t aZ[2] = {z4, z4}, aR[2] = {z4, z4};
        #pragma unroll
        for (int kt = 0; kt < 8; ++kt) {
            bf8_t hf  = LD8(&sA_hd[(kt * 64 + lane) * 8]);
            bf8_t wr0 = LD8(&sWh1[((2 * w + 0) * 8 + kt) * 512 + lane * 8]);
            bf8_t wr1 = LD8(&sWh1[((2 * w + 1) * 8 + kt) * 512 + lane * 8]);
            aZ[0] = MF(hf, whz[0][kt], aZ[0]);
            aZ[1] = MF(hf, whz[1][kt], aZ[1]);
            aR[0] = MF(hf, wr0, aR[0]);
            aR[1] = MF(hf, wr1, aR[1]);
        }
        #pragma unroll
        for (int nt = 0; nt < 2; ++nt) {
            aZ[nt] = MF(xf0, wxz[nt][0], aZ[nt]); aZ[nt] = MF(xf1, wxz[nt][1], aZ[nt]);
            aZ[nt] = MF(mf0, wmz[nt][0], aZ[nt]); aZ[nt] = MF(mf1, wmz[nt][1], aZ[nt]);
            aR[nt] = MF(xf0, wxr[nt][0], aR[nt]); aR[nt] = MF(xf1, wxr[nt][1], aR[nt]);
            aR[nt] = MF(mf0, wmr[nt][0], aR[nt]); aR[nt] = MF(mf1, wmr[nt][1], aR[nt]);
        }
        bf8_t wxh[2][2], wmh[2][2];
        #pragma unroll
        for (int nt = 0; nt < 2; ++nt)
            #pragma unroll
            for (int kt = 0; kt < 2; ++kt) {
                wxh[nt][kt] = LD8(BA(pk + OFF_WX + 32768, 2 * w + nt, 2, kt, lane));
                wmh[nt][kt] = LD8(BA(pk + OFF_WM + 32768, 2 * w + nt, 2, kt, lane));
            }
        #pragma unroll
        for (int nt = 0; nt < 2; ++nt) {
            const int col = w * 32 + nt * 16 + c15;
            #pragma unroll
            for (int q = 0; q < 4; ++q) {
                const int r = rowb + q;
                float z  = 1.f / (1.f + __expf(-(aZ[nt][q] + bz[nt])));
                float rr = 1.f / (1.f + __expf(-(aR[nt][q] + brr[nt])));
                zz[nt][q] = z;
                sA_rhd[(w * 64 + ((col & 31) >> 3) * 16 + r) * 8 + (col & 7)] =
                    (short)f2bf(rr * hd_cd[nt][q]);
            }
        }
        lds_sync();   // bar1

        // ===== PH3: h_tilde + h update =====
        f4_t aH[2] = {z4, z4};
        #pragma unroll
        for (int kt = 0; kt < 8; ++kt) {
            bf8_t rf = LD8(&sA_rhd[(kt * 64 + lane) * 8]);
            aH[0] = MF(rf, whh[0][kt], aH[0]);
            aH[1] = MF(rf, whh[1][kt], aH[1]);
        }
        #pragma unroll
        for (int nt = 0; nt < 2; ++nt) {
            aH[nt] = MF(xf0, wxh[nt][0], aH[nt]); aH[nt] = MF(xf1, wxh[nt][1], aH[nt]);
            aH[nt] = MF(mf0, wmh[nt][0], aH[nt]); aH[nt] = MF(mf1, wmh[nt][1], aH[nt]);
        }
        #pragma unroll
        for (int nt = 0; nt < 2; ++nt) {
            const int col = w * 32 + nt * 16 + c15;
            #pragma unroll
            for (int q = 0; q < 4; ++q) {
                const int r = rowb + q;
                float pre = aH[nt][q] + bh[nt];
                float a = fabsf(pre), e = __expf(-2.f * a);
                float th = copysignf((1.f - e) / (1.f + e), pre);
                float hn = (1.f - zz[nt][q]) * hd_cd[nt][q] + zz[nt][q] * th;
                h_cd[nt][q] = hn;
                sh_hb[r][col] = f2bf(hn);
            }
        }
        lds_sync();   // bar2
    }

    // ---- classifier ----
    #pragma unroll
    for (int rr2 = 0; rr2 < 2; ++rr2) {
        const int row = w * 2 + rr2;
        ushort4 hb = *(const ushort4*)&sh_hb[row][lane * 4];
        float4 wv  = *(const float4*)&W_cls[lane * 4];
        float p = bf2f(hb.x) * wv.x + bf2f(hb.y) * wv.y +
                  bf2f(hb.z) * wv.z + bf2f(hb.w) * wv.w;
        #pragma unroll
        for (int o = 32; o > 0; o >>= 1) p += __shfl_down(p, o, 64);
        if (lane == 0) out[b0 + row] = p + b_cls[0];
    }
}

// ---------------------------------------------------------------------------
// Fallback (R2 kernel) if ws_size < WS_NEED — not expected.
// ---------------------------------------------------------------------------
__global__ __launch_bounds__(512, 2) void grud_main(
    const float* __restrict__ X, const float* __restrict__ M, const float* __restrict__ Dl,
    const float* __restrict__ x_mean, const float* __restrict__ b_gx,
    const float* __restrict__ b_gh, const float* __restrict__ b_g,
    const float* __restrict__ W_cls, const float* __restrict__ b_cls,
    const short* __restrict__ pk, float* __restrict__ out)
{
    __shared__ float sh_h [BB][Hn];
    __shared__ float sh_xp[BB][Dn];
    __shared__ float sh_x [BB][Dn];
    __shared__ float sh_m [BB][Dn];
    __shared__ short sA_d  [2 * 64 * 8];
    __shared__ short sA_m  [2 * 64 * 8];
    __shared__ short sA_xh [2 * 64 * 8];
    __shared__ short sA_hd [8 * 64 * 8];
    __shared__ short sA_rhd[8 * 64 * 8];
    __shared__ float sh_bgx[Dn], sh_xmean[Dn], sh_bgh[Hn], sh_bg[3][Hn];

    const int tid  = threadIdx.x;
    const int w    = tid >> 6, lane = tid & 63;
    const int b0   = blockIdx.x * BB;
    const int rowb = (lane >> 4) * 4;
    const int c15  = lane & 15;

    for (int i = tid; i < BB * Hn; i += 512) (&sh_h[0][0])[i]  = 0.f;
    for (int i = tid; i < BB * Dn; i += 512) (&sh_xp[0][0])[i] = 0.f;
    if (tid < Dn) { sh_bgx[tid] = b_gx[tid]; sh_xmean[tid] = x_mean[tid]; }
    if (tid < Hn) sh_bgh[tid] = b_gh[tid];
    for (int i = tid; i < 3 * Hn; i += 512) (&sh_bg[0][0])[i] = b_g[i];
    __syncthreads();

    const short* whp  = pk + OFF_WH;
    const short* wxp  = pk + OFF_WX;
    const short* wmp  = pk + OFF_WM;
    const short* wghp = pk + OFF_WGH;
    const short* wgxp = pk + OFF_WGX;

    for (int t = 0; t < Tn; ++t) {
        if (tid < 128) {
            const int kt2 = tid >> 6, lf = tid & 63;
            const int r = lf & 15, db = kt2 * 32 + ((lf >> 4) << 3);
            const float* p = Dl + ((size_t)(b0 + r) * Tn + t) * Dn + db;
            float4 a = *(const float4*)p, b = *(const float4*)(p + 4);
            bf8_t v;
            v[0]=(short)f2bf(a.x); v[1]=(short)f2bf(a.y); v[2]=(short)f2bf(a.z); v[3]=(short)f2bf(a.w);
            v[4]=(short)f2bf(b.x); v[5]=(short)f2bf(b.y); v[6]=(short)f2bf(b.z); v[7]=(short)f2bf(b.w);
            *(bf8_t*)&sA_d[tid * 8] = v;
        } else if (tid < 256) {
            const int s2 = tid - 128;
            const int kt2 = s2 >> 6, lf = s2 & 63;
            const int r = lf & 15, db = kt2 * 32 + ((lf >> 4) << 3);
            const float* p = M + ((size_t)(b0 + r) * Tn + t) * Dn + db;
            float4 a = *(const float4*)p, b = *(const float4*)(p + 4);
            bf8_t v;
            v[0]=(short)f2bf(a.x); v[1]=(short)f2bf(a.y); v[2]=(short)f2bf(a.z); v[3]=(short)f2bf(a.w);
            v[4]=(short)f2bf(b.x); v[5]=(short)f2bf(b.y); v[6]=(short)f2bf(b.z); v[7]=(short)f2bf(b.w);
            *(bf8_t*)&sA_m[s2 * 8] = v;
        } else {
            const int s2 = tid - 256, r = s2 >> 4, seg = (s2 & 15) * 4;
            const size_t off = ((size_t)(b0 + r) * Tn + t) * Dn + seg;
            *(float4*)&sh_x[r][seg] = *(const float4*)(X + off);
            *(float4*)&sh_m[r][seg] = *(const float4*)(M + off);
        }
        __syncthreads();

        bf8_t df0 = *(const bf8_t*)&sA_d[(0 * 64 + lane) * 8];
        bf8_t df1 = *(const bf8_t*)&sA_d[(1 * 64 + lane) * 8];
        f4_t accG0 = {0.f,0.f,0.f,0.f}, accG1 = {0.f,0.f,0.f,0.f};
        accG0 = MFp(df0, BA(wghp, 2*w+0, 2, 0, lane), accG0);
        accG0 = MFp(df1, BA(wghp, 2*w+0, 2, 1, lane), accG0);
        accG1 = MFp(df0, BA(wghp, 2*w+1, 2, 0, lane), accG1);
        accG1 = MFp(df1, BA(wghp, 2*w+1, 2, 1, lane), accG1);
        if (w < 4) {
            f4_t aGx = {0.f,0.f,0.f,0.f};
            aGx = MFp(df0, BA(wgxp, w, 2, 0, lane), aGx);
            aGx = MFp(df1, BA(wgxp, w, 2, 1, lane), aGx);
            const int col = w * 16 + c15;
            #pragma unroll
            for (int q = 0; q < 4; ++q) {
                const int r = rowb + q;
                float gxs = __expf(-fmaxf(aGx[q] + sh_bgx[col], 0.f));
                float mvs = sh_m[r][col], xvs = sh_x[r][col], xpv = sh_xp[r][col];
                float xh  = mvs * xvs + (1.f - mvs) * (gxs * xpv + (1.f - gxs) * sh_xmean[col]);
                sh_xp[r][col] = mvs * xvs + (1.f - mvs) * xpv;
                sA_xh[((col >> 5) * 64 + (((col & 31) >> 3) << 4) + r) * 8 + (col & 7)]
                    = (short)f2bf(xh);
            }
        }
        __syncthreads();

        bf8_t xf0 = *(const bf8_t*)&sA_xh[(0 * 64 + lane) * 8];
        bf8_t xf1 = *(const bf8_t*)&sA_xh[(1 * 64 + lane) * 8];
        bf8_t mf0 = *(const bf8_t*)&sA_m [(0 * 64 + lane) * 8];
        bf8_t mf1 = *(const bf8_t*)&sA_m [(1 * 64 + lane) * 8];
        f4_t accP[3][2];
        #pragma unroll
        for (int g = 0; g < 3; ++g) {
            const short* bx = wxp + (size_t)g * 16384;
            const short* bm = wmp + (size_t)g * 16384;
            #pragma unroll
            for (int nt = 0; nt < 2; ++nt) {
                const int ntG = 2 * w + nt;
                f4_t a = {0.f,0.f,0.f,0.f};
                a = MFp(xf0, BA(bx, ntG, 2, 0, lane), a);
                a = MFp(xf1, BA(bx, ntG, 2, 1, lane), a);
                a = MFp(mf0, BA(bm, ntG, 2, 0, lane), a);
                a = MFp(mf1, BA(bm, ntG, 2, 1, lane), a);
                accP[g][nt] = a;
            }
        }
        float hd2[2][4];
        #pragma unroll
        for (int nt = 0; nt < 2; ++nt) {
            const f4_t aG = nt ? accG1 : accG0;
            const int col = w * 32 + nt * 16 + c15;
            #pragma unroll
            for (int q = 0; q < 4; ++q) {
                const int r = rowb + q;
                float gh2 = __expf(-fmaxf(aG[q] + sh_bgh[col], 0.f));
                float hdv = gh2 * sh_h[r][col];
                hd2[nt][q] = hdv;
                sA_hd[((size_t)w * 64 + (((col & 31) >> 3) << 4) + r) * 8 + (col & 7)]
                    = (short)f2bf(hdv);
            }
        }
        __syncthreads();

        f4_t accZ[2] = {accP[0][0], accP[0][1]};
        f4_t accR[2] = {accP[1][0], accP[1][1]};
        #pragma unroll
        for (int kt = 0; kt < 8; ++kt) {
            bf8_t hf = *(const bf8_t*)&sA_hd[(kt * 64 + lane) * 8];
            #pragma unroll
            for (int nt = 0; nt < 2; ++nt) {
                const int ntG = 2 * w + nt;
                accZ[nt] = MFp(hf, BA(whp + 0 * 65536, ntG, 8, kt, lane), accZ[nt]);
                accR[nt] = MFp(hf, BA(whp + 1 * 65536, ntG, 8, kt, lane), accR[nt]);
            }
        }
        float zz2[2][4];
        #pragma unroll
        for (int nt = 0; nt < 2; ++nt) {
            const int col = w * 32 + nt * 16 + c15;
            #pragma unroll
            for (int q = 0; q < 4; ++q) {
                const int r = rowb + q;
                float z  = 1.f / (1.f + __expf(-(accZ[nt][q] + sh_bg[0][col])));
                float rv = 1.f / (1.f + __expf(-(accR[nt][q] + sh_bg[1][col])));
                zz2[nt][q] = z;
                sA_rhd[((size_t)w * 64 + (((col & 31) >> 3) << 4) + r) * 8 + (col & 7)]
                    = (short)f2bf(rv * hd2[nt][q]);
            }
        }
        __syncthreads();

        f4_t accH[2] = {accP[2][0], accP[2][1]};
        #pragma unroll
        for (int kt = 0; kt < 8; ++kt) {
            bf8_t hf = *(const bf8_t*)&sA_rhd[(kt * 64 + lane) * 8];
            #pragma unroll
            for (int nt = 0; nt < 2; ++nt)
                accH[nt] = MFp(hf, BA(whp + 2 * 65536, 2 * w + nt, 8, kt, lane), accH[nt]);
        }
        #pragma unroll
        for (int nt = 0; nt < 2; ++nt) {
            const int col = w * 32 + nt * 16 + c15;
            #pragma unroll
            for (int q = 0; q < 4; ++q) {
                const int r = rowb + q;
                float pre = accH[nt][q] + sh_bg[2][col];
                float a = fabsf(pre), e = __expf(-2.f * a);
                float th = copysignf((1.f - e) / (1.f + e), pre);
                sh_h[r][col] = (1.f - zz2[nt][q]) * hd2[nt][q] + zz2[nt][q] * th;
            }
        }
        __syncthreads();
    }

    if (tid < BB) {
        float s2 = 0.f;
        for (int k = 0; k < Hn; ++k) s2 = fmaf(sh_h[tid][k], W_cls[k], s2);
        out[b0 + tid] = s2 + b_cls[0];
    }
}

extern "C" void kernel_launch(void* const* d_in, const int* in_sizes, int n_in,
                              void* d_out, int out_size, void* d_ws, size_t ws_size,
                              hipStream_t stream) {
    const float* X      = (const float*)d_in[0];
    const float* M      = (const float*)d_in[1];
    const float* Dl     = (const float*)d_in[2];
    const float* x_mean = (const float*)d_in[3];
    const float* W_gx   = (const float*)d_in[4];
    const float* b_gx   = (const float*)d_in[5];
    const float* W_gh   = (const float*)d_in[6];
    const float* b_gh   = (const float*)d_in[7];
    const float* W_x    = (const float*)d_in[8];
    const float* W_h    = (const float*)d_in[9];
    const float* W_m    = (const float*)d_in[10];
    const float* b_g    = (const float*)d_in[11];
    const float* W_cls  = (const float*)d_in[12];
    const float* b_cls  = (const float*)d_in[13];
    float* out = (float*)d_out;
    short* pk  = (short*)d_ws;

    hipLaunchKernelGGL(pack_weights, dim3((PACK_SLOTS + 255) / 256), dim3(256), 0, stream,
                       W_gx, W_gh, W_x, W_h, W_m, pk);

    if (ws_size >= WS_NEED) {
        float*          gxbuf = (float*)((char*)d_ws + GX_OFF);
        unsigned short* ghbuf = (unsigned short*)((char*)d_ws + GH_OFF);
        hipLaunchKernelGGL(grud_prepass, dim3(NBLK * Tn), dim3(256), 0, stream,
                           Dl, b_gx, b_gh, pk, gxbuf, ghbuf);
        hipLaunchKernelGGL(grud_rec8, dim3(NBLK), dim3(512), 0, stream,
                           X, M, x_mean, b_g, W_cls, b_cls, pk, gxbuf, ghbuf, out);
    } else {
        hipLaunchKernelGGL(grud_main, dim3(NBLK), dim3(512), 0, stream,
                           X, M, Dl, x_mean, b_gx, b_gh, b_g, W_cls, b_cls, pk, out);
    }
}